// Round 7
// baseline (1022.783 us; speedup 1.0000x reference)
//
#include <hip/hip_runtime.h>

// ---------- types / helpers ----------
typedef __attribute__((ext_vector_type(8))) _Float16 f16x8;
typedef __attribute__((ext_vector_type(2))) _Float16 h2;
typedef __attribute__((ext_vector_type(4))) float f32x4;
typedef __attribute__((ext_vector_type(2))) float f32x2;
typedef __attribute__((ext_vector_type(4))) unsigned uint4_t;
typedef __attribute__((ext_vector_type(2))) unsigned uint2_t;

__device__ __forceinline__ h2 pkrtz(float a, float b) {
    return __builtin_bit_cast(h2, __builtin_amdgcn_cvt_pkrtz(a, b));   // v_cvt_pkrtz_f16_f32
}
__device__ __forceinline__ unsigned h2u(h2 v) { return __builtin_bit_cast(unsigned, v); }
__device__ __forceinline__ h2 u2h(unsigned u) { return __builtin_bit_cast(h2, u); }
__device__ __forceinline__ short f2h(float f) { return __builtin_bit_cast(short, (_Float16)f); }

// ws layout (bytes)
#define OFF_W1T 0L            // 32768
#define OFF_W2T 32768L        // 16384
#define OFF_W3T 49152L        // 32768
#define OFF_W4T 81920L        // 16384
#define OFF_DWH 98304L        // 4608
#define OFF_DBH 102912L       // 512
#define OFF_WATT 103424L      // 4096
#define OFF_GPART 107520L     // 16384*64*4 = 4194304
#define OFF_T 4301824L        // 524288*128*2 = 134217728

// ---------- K0: weight transpose + fp16 cast ----------
__global__ __launch_bounds__(256) void k_prep(
    const float* __restrict__ w1, const float* __restrict__ w2,
    const float* __restrict__ w3, const float* __restrict__ w4,
    const float* __restrict__ dww, const float* __restrict__ dwb,
    short* __restrict__ w1t, short* __restrict__ w2t,
    short* __restrict__ w3t, short* __restrict__ w4t,
    short* __restrict__ dwh, short* __restrict__ dbh)
{
    int id = blockIdx.x * 256 + threadIdx.x;
    if (id < 64 * 256) {
        int ci = id >> 8, co = id & 255;
        w1t[co * 64 + ci] = f2h(w1[id]);
        w3t[co * 64 + ci] = f2h(w3[id]);
    }
    if (id < 128 * 64) {
        int ci = id >> 6, co = id & 63;
        w2t[co * 128 + ci] = f2h(w2[id]);
        w4t[co * 128 + ci] = f2h(w4[id]);
    }
    if (id < 9 * 256) dwh[id] = f2h(dww[id]);
    if (id < 256)     dbh[id] = f2h(dwb[id]);
}

// ---------- K_A: LN1 + pw1(MFMA) + dw3x3 + gate + GAP partials ----------
// LDS: u tile [100 rows][128 shorts], XOR-swizzled (byte ^= (row&7)<<4).
__global__ __launch_bounds__(256) void k_a(
    const float* __restrict__ x, const float* __restrict__ ln1g, const float* __restrict__ ln1b,
    const short* __restrict__ w1t, const float* __restrict__ b1,
    const short* __restrict__ dwh, const short* __restrict__ dbh,
    short* __restrict__ t, float* __restrict__ gpart)
{
    __shared__ short uh[100 * 128];   // 25600 B
    const int blk = blockIdx.x;
    const int cs  = blk & 1;
    const int txy = blk >> 1;
    const int tx  = txy & 31;
    const int ty  = (txy >> 5) & 31;
    const int b   = txy >> 10;
    const int tid = threadIdx.x;
    const int lane = tid & 63;
    const int wave = tid >> 6;
    const int m    = lane & 15;
    const int quad = lane >> 4;

    // ---- phase 1: two pixel-slots per wave (pA = wave*16+m, pB = pA+64)
    const int pA = wave * 16 + m;
    const int pB = pA + 64;
    const int hyA = (pA * 205) >> 11, hxA = pA - hyA * 10;
    const int hyB = (pB * 205) >> 11, hxB = pB - hyB * 10;
    const int gyA = ty * 8 + hyA - 1, gxA = tx * 8 + hxA - 1;
    const int gyB = ty * 8 + hyB - 1, gxB = tx * 8 + hxB - 1;
    const bool imgA = gyA >= 0 && gyA < 256 && gxA >= 0 && gxA < 256;  // pA<100 always
    const bool imgB = (pB < 100) && gyB >= 0 && gyB < 256 && gxB >= 0 && gxB < 256;
    const bool aliveB = (wave < 3);   // wave3's B slot (p>=112) fully dead

    f32x4 fA[4], fB[4];
#pragma unroll
    for (int i = 0; i < 4; ++i) {
        fA[i] = (f32x4){0.f,0.f,0.f,0.f};
        fB[i] = (f32x4){0.f,0.f,0.f,0.f};
    }
    if (imgA) {
        const float* xr = x + ((long)((b * 256 + gyA) * 256 + gxA)) * 64 + quad * 8;
        fA[0] = *(const f32x4*)(xr);      fA[1] = *(const f32x4*)(xr + 4);
        fA[2] = *(const f32x4*)(xr + 32); fA[3] = *(const f32x4*)(xr + 36);
    }
    if (imgB) {
        const float* xr = x + ((long)((b * 256 + gyB) * 256 + gxB)) * 64 + quad * 8;
        fB[0] = *(const f32x4*)(xr);      fB[1] = *(const f32x4*)(xr + 4);
        fB[2] = *(const f32x4*)(xr + 32); fB[3] = *(const f32x4*)(xr + 36);
    }

    // LN affine params loaded once, shared by both slots
    f32x4 g0 = *(const f32x4*)(ln1g + quad * 8);
    f32x4 g1 = *(const f32x4*)(ln1g + quad * 8 + 4);
    f32x4 g2 = *(const f32x4*)(ln1g + 32 + quad * 8);
    f32x4 g3 = *(const f32x4*)(ln1g + 32 + quad * 8 + 4);
    f32x4 c0 = *(const f32x4*)(ln1b + quad * 8);
    f32x4 c1 = *(const f32x4*)(ln1b + quad * 8 + 4);
    f32x4 c2 = *(const f32x4*)(ln1b + 32 + quad * 8);
    f32x4 c3 = *(const f32x4*)(ln1b + 32 + quad * 8 + 4);

    f16x8 a0A = {0,0,0,0,0,0,0,0}, a1A = {0,0,0,0,0,0,0,0};
    f16x8 a0B = {0,0,0,0,0,0,0,0}, a1B = {0,0,0,0,0,0,0,0};

    if (imgA) {
        float s  = 0.f, s2 = 0.f;
#pragma unroll
        for (int i = 0; i < 4; ++i)
#pragma unroll
            for (int r = 0; r < 4; ++r) { s += fA[i][r]; s2 += fA[i][r] * fA[i][r]; }
        s  += __shfl_xor(s, 16);  s  += __shfl_xor(s, 32);
        s2 += __shfl_xor(s2, 16); s2 += __shfl_xor(s2, 32);
        float mean = s * 0.015625f;
        float var  = s2 * 0.015625f - mean * mean;
        float rs   = rsqrtf(var + 1e-6f);
        float mrs  = mean * rs;
        uint4_t ra, rb;
#define LNP(va,vb,ga,gb,ca,cb) h2u(pkrtz(((va)*rs - mrs)*(ga) + (ca), ((vb)*rs - mrs)*(gb) + (cb)))
        ra[0] = LNP(fA[0][0],fA[0][1],g0[0],g0[1],c0[0],c0[1]);
        ra[1] = LNP(fA[0][2],fA[0][3],g0[2],g0[3],c0[2],c0[3]);
        ra[2] = LNP(fA[1][0],fA[1][1],g1[0],g1[1],c1[0],c1[1]);
        ra[3] = LNP(fA[1][2],fA[1][3],g1[2],g1[3],c1[2],c1[3]);
        rb[0] = LNP(fA[2][0],fA[2][1],g2[0],g2[1],c2[0],c2[1]);
        rb[1] = LNP(fA[2][2],fA[2][3],g2[2],g2[3],c2[2],c2[3]);
        rb[2] = LNP(fA[3][0],fA[3][1],g3[0],g3[1],c3[0],c3[1]);
        rb[3] = LNP(fA[3][2],fA[3][3],g3[2],g3[3],c3[2],c3[3]);
        a0A = __builtin_bit_cast(f16x8, ra);
        a1A = __builtin_bit_cast(f16x8, rb);
    }
    if (imgB) {
        float s  = 0.f, s2 = 0.f;
#pragma unroll
        for (int i = 0; i < 4; ++i)
#pragma unroll
            for (int r = 0; r < 4; ++r) { s += fB[i][r]; s2 += fB[i][r] * fB[i][r]; }
        s  += __shfl_xor(s, 16);  s  += __shfl_xor(s, 32);
        s2 += __shfl_xor(s2, 16); s2 += __shfl_xor(s2, 32);
        float mean = s * 0.015625f;
        float var  = s2 * 0.015625f - mean * mean;
        float rs   = rsqrtf(var + 1e-6f);
        float mrs  = mean * rs;
        uint4_t ra, rb;
        ra[0] = LNP(fB[0][0],fB[0][1],g0[0],g0[1],c0[0],c0[1]);
        ra[1] = LNP(fB[0][2],fB[0][3],g0[2],g0[3],c0[2],c0[3]);
        ra[2] = LNP(fB[1][0],fB[1][1],g1[0],g1[1],c1[0],c1[1]);
        ra[3] = LNP(fB[1][2],fB[1][3],g1[2],g1[3],c1[2],c1[3]);
        rb[0] = LNP(fB[2][0],fB[2][1],g2[0],g2[1],c2[0],c2[1]);
        rb[1] = LNP(fB[2][2],fB[2][3],g2[2],g2[3],c2[2],c2[3]);
        rb[2] = LNP(fB[3][0],fB[3][1],g3[0],g3[1],c3[0],c3[1]);
        rb[3] = LNP(fB[3][2],fB[3][3],g3[2],g3[3],c3[2],c3[3]);
#undef LNP
        a0B = __builtin_bit_cast(f16x8, ra);
        a1B = __builtin_bit_cast(f16x8, rb);
    }

    // MFMA: each w1t/b1 fragment loaded once, feeds both slots
    char* uhc = (char*)uh;
    __builtin_amdgcn_s_setprio(1);
#pragma unroll
    for (int cot = 0; cot < 8; ++cot) {
        const int cob = (cot < 4) ? (cs * 64 + cot * 16) : (128 + cs * 64 + (cot - 4) * 16);
        const f16x8 wlo = __builtin_bit_cast(f16x8, *(const uint4_t*)(w1t + (cob + m) * 64 + quad * 8));
        const f16x8 whi = __builtin_bit_cast(f16x8, *(const uint4_t*)(w1t + (cob + m) * 64 + 32 + quad * 8));
        const f32x4 bv = *(const f32x4*)(b1 + cob + quad * 4);
        {
            f32x4 acc = {0.f,0.f,0.f,0.f};
            acc = __builtin_amdgcn_mfma_f32_16x16x32_f16(wlo, a0A, acc, 0, 0, 0);
            acc = __builtin_amdgcn_mfma_f32_16x16x32_f16(whi, a1A, acc, 0, 0, 0);
            uint2_t pk;
            pk[0] = imgA ? h2u(pkrtz(acc[0] + bv[0], acc[1] + bv[1])) : 0u;
            pk[1] = imgA ? h2u(pkrtz(acc[2] + bv[2], acc[3] + bv[3])) : 0u;
            int off = (pA * 256 + cot * 32 + quad * 8) ^ ((pA & 7) << 4);
            *(uint2_t*)(uhc + off) = pk;
        }
        if (aliveB) {
            f32x4 acc = {0.f,0.f,0.f,0.f};
            acc = __builtin_amdgcn_mfma_f32_16x16x32_f16(wlo, a0B, acc, 0, 0, 0);
            acc = __builtin_amdgcn_mfma_f32_16x16x32_f16(whi, a1B, acc, 0, 0, 0);
            if (pB < 100) {
                uint2_t pk;
                pk[0] = imgB ? h2u(pkrtz(acc[0] + bv[0], acc[1] + bv[1])) : 0u;
                pk[1] = imgB ? h2u(pkrtz(acc[2] + bv[2], acc[3] + bv[3])) : 0u;
                int off = (pB * 256 + cot * 32 + quad * 8) ^ ((pB & 7) << 4);
                *(uint2_t*)(uhc + off) = pk;
            }
        }
    }
    __builtin_amdgcn_s_setprio(0);
    __syncthreads();

    // ---- phase 2: dw3x3 + gate, packed fp16 ----
    const int y = lane >> 3, xx = lane & 7;
    const int cq = wave;
    const int gc0 = cs * 64 + cq * 16;
    const long gpx = ((long)(b * 256 + ty * 8 + y) * 256) + tx * 8 + xx;

    h2 A1[8], A2[8];
#pragma unroll
    for (int j = 0; j < 8; ++j) {
        A1[j] = u2h(0u);
        A2[j] = u2h(0u);
    }
#pragma unroll
    for (int dy = 0; dy < 3; ++dy)
#pragma unroll
    for (int dx = 0; dx < 3; ++dx) {
        int h = (y + dy) * 10 + (xx + dx);
        int sw = (h & 7) << 4;
        int b0 = h * 256 + cq * 32;
        uint4_t u1l  = *(const uint4_t*)(uhc + ((b0)       ^ sw));
        uint4_t u1h  = *(const uint4_t*)(uhc + ((b0 + 16)  ^ sw));
        uint4_t u2l  = *(const uint4_t*)(uhc + ((b0 + 128) ^ sw));
        uint4_t u2hv = *(const uint4_t*)(uhc + ((b0 + 144) ^ sw));
        const uint4_t* wp = (const uint4_t*)(dwh + (dy * 3 + dx) * 256 + gc0);
        const uint4_t* vp = (const uint4_t*)(dwh + (dy * 3 + dx) * 256 + 128 + gc0);
        uint4_t w1l = wp[0], w1h = wp[1];
        uint4_t w2l = vp[0], w2h = vp[1];
#pragma unroll
        for (int j = 0; j < 4; ++j) {
            A1[j]     += u2h(u1l[j])  * u2h(w1l[j]);
            A1[j + 4] += u2h(u1h[j])  * u2h(w1h[j]);
            A2[j]     += u2h(u2l[j])  * u2h(w2l[j]);
            A2[j + 4] += u2h(u2hv[j]) * u2h(w2h[j]);
        }
    }
    const uint4_t* bp1 = (const uint4_t*)(dbh + gc0);
    const uint4_t* bp2 = (const uint4_t*)(dbh + 128 + gc0);
    uint4_t b1l = bp1[0], b1h = bp1[1];
    uint4_t b2l = bp2[0], b2h = bp2[1];
    uint4_t s0, s1;
#pragma unroll
    for (int j = 0; j < 4; ++j) {
        h2 t0 = (A1[j]     + u2h(b1l[j])) * (A2[j]     + u2h(b2l[j]));
        h2 t1 = (A1[j + 4] + u2h(b1h[j])) * (A2[j + 4] + u2h(b2h[j]));
        s0[j] = h2u(t0);
        s1[j] = h2u(t1);
    }
    *(uint4_t*)(t + gpx * 128 + gc0)     = s0;
    *(uint4_t*)(t + gpx * 128 + gc0 + 8) = s1;

    // ---- GAP partials: packed-f16 butterfly over the wave's 64 pixels ----
#pragma unroll
    for (int st = 1; st < 64; st <<= 1) {
#pragma unroll
        for (int j = 0; j < 4; ++j) {
            s0[j] = h2u(u2h(s0[j]) + u2h((unsigned)__shfl_xor((int)s0[j], st)));
            s1[j] = h2u(u2h(s1[j]) + u2h((unsigned)__shfl_xor((int)s1[j], st)));
        }
    }
    if (lane == 0) {
        float* gp = gpart + (long)blk * 64 + cq * 16;
#pragma unroll
        for (int j = 0; j < 4; ++j) {
            h2 v0 = u2h(s0[j]), v1 = u2h(s1[j]);
            f32x2 w0 = {(float)v0[0], (float)v0[1]};
            f32x2 w1 = {(float)v1[0], (float)v1[1]};
            *(f32x2*)(gp + 2 * j)     = w0;
            *(f32x2*)(gp + 8 + 2 * j) = w1;
        }
    }
}

// ---------- K_S: GAP final reduce + SCA matmul (8 blocks, one per batch) ----------
__global__ __launch_bounds__(256) void k_sca(
    const float* __restrict__ gpart, const float* __restrict__ scaw,
    const float* __restrict__ scab, float* __restrict__ watt)
{
    __shared__ float red[2][128];
    __shared__ float gn[128];
    const int b = blockIdx.x;
    const int tid = threadIdx.x;
    const int c = tid & 127, p = tid >> 7;
    const int cs = c >> 6, lc = c & 63;
    float s = 0.f;
    // blocks for batch b: blk = (b*1024 + txy)*2 + cs -> stride 128 floats
    const float* gp = gpart + ((long)(b * 1024) * 2 + cs) * 64 + lc;
    for (int txy = p; txy < 1024; txy += 2)
        s += gp[(long)txy * 128];
    red[p][c] = s;
    __syncthreads();
    if (tid < 128) gn[c] = (red[0][c] + red[1][c]) * (1.0f / 65536.0f);
    __syncthreads();
    if (tid < 128) {
        float acc = scab[c];
        for (int ci = 0; ci < 128; ++ci) acc += gn[ci] * scaw[ci * 128 + c];
        watt[b * 128 + c] = acc;
    }
}

// ---------- K_B: pw2 + residual + LN2 + pw3 + gate + pw4 + residual ----------
// xl/zt are PER-WAVE-PRIVATE slabs: no __syncthreads anywhere.
// Register diet: only ONE bfr/zb fragment live at a time (kh-outer MFMA loops,
// numerically identical order), target <=64 VGPR -> 8 waves/SIMD step
// (LDS caps at 6 blocks/CU = 75%). launch_bounds(256,8) pins the budget.
#define XLST 72
#define ZTST 136
__global__ __launch_bounds__(256, 8) void k_b(
    const short* __restrict__ t, const float* __restrict__ watt,
    const short* __restrict__ w2t, const float* __restrict__ b2,
    const float* __restrict__ x, const float* __restrict__ beta,
    const float* __restrict__ ln2g, const float* __restrict__ ln2b,
    const short* __restrict__ w3t, const float* __restrict__ b3,
    const short* __restrict__ w4t, const float* __restrict__ b4,
    const float* __restrict__ gamma, float* __restrict__ out)
{
    __shared__ short xl[4][16 * XLST];
    __shared__ short zt[4][16 * ZTST];
    const int lane = threadIdx.x & 63;
    const int wave = threadIdx.x >> 6;
    const int m = lane & 15, quad = lane >> 4;
    const long px0 = (long)blockIdx.x * 64 + wave * 16;
    const int b = (int)(px0 >> 16);
    const float* wa = watt + b * 128;

    // residual x loads first: latency hides under t-load + pw2 MFMA
    f32x4 xv[4];
#pragma unroll
    for (int nt = 0; nt < 4; ++nt)
        xv[nt] = *(const f32x4*)(x + (px0 + m) * 64 + nt * 16 + quad * 4);

    const short* tr = t + (px0 + m) * 128;
    f32x4 acc2[4];
#pragma unroll
    for (int nt = 0; nt < 4; ++nt) { f32x4 z = {0.f,0.f,0.f,0.f}; acc2[nt] = z; }
    __builtin_amdgcn_s_setprio(1);
#pragma unroll
    for (int kh = 0; kh < 4; ++kh) {
        uint4_t tvv = *(const uint4_t*)(tr + kh * 32 + quad * 8);
        f32x4 w0  = *(const f32x4*)(wa + kh * 32 + quad * 8);
        f32x4 w1v = *(const f32x4*)(wa + kh * 32 + quad * 8 + 4);
        uint4_t o;
        o[0] = h2u(u2h(tvv[0]) * pkrtz(w0[0],  w0[1]));
        o[1] = h2u(u2h(tvv[1]) * pkrtz(w0[2],  w0[3]));
        o[2] = h2u(u2h(tvv[2]) * pkrtz(w1v[0], w1v[1]));
        o[3] = h2u(u2h(tvv[3]) * pkrtz(w1v[2], w1v[3]));
        f16x8 bfr = __builtin_bit_cast(f16x8, o);
#pragma unroll
        for (int nt = 0; nt < 4; ++nt) {
            f16x8 aw = __builtin_bit_cast(f16x8,
                *(const uint4_t*)(w2t + (nt * 16 + m) * 128 + kh * 32 + quad * 8));
            acc2[nt] = __builtin_amdgcn_mfma_f32_16x16x32_f16(aw, bfr, acc2[nt], 0, 0, 0);
        }
    }
    __builtin_amdgcn_s_setprio(0);
    float x1v[4][4];
#pragma unroll
    for (int nt = 0; nt < 4; ++nt) {
        int cob = nt * 16 + quad * 4;
        f32x4 bb = *(const f32x4*)(b2 + cob);
        f32x4 be = *(const f32x4*)(beta + cob);
#pragma unroll
        for (int r = 0; r < 4; ++r)
            x1v[nt][r] = xv[nt][r] + (acc2[nt][r] + bb[r]) * be[r];
    }
    float s = 0.f, s2 = 0.f;
#pragma unroll
    for (int nt = 0; nt < 4; ++nt)
#pragma unroll
        for (int r = 0; r < 4; ++r) { s += x1v[nt][r]; s2 += x1v[nt][r] * x1v[nt][r]; }
    s  += __shfl_xor(s, 16);  s  += __shfl_xor(s, 32);
    s2 += __shfl_xor(s2, 16); s2 += __shfl_xor(s2, 32);
    float mean = s * 0.015625f;
    float var  = s2 * 0.015625f - mean * mean;
    float rs   = rsqrtf(var + 1e-6f);
    float mrs  = mean * rs;
#pragma unroll
    for (int nt = 0; nt < 4; ++nt) {
        int cob = nt * 16 + quad * 4;
        f32x4 gg = *(const f32x4*)(ln2g + cob);
        f32x4 cc = *(const f32x4*)(ln2b + cob);
        float v0 = (x1v[nt][0] * rs - mrs) * gg[0] + cc[0];
        float v1 = (x1v[nt][1] * rs - mrs) * gg[1] + cc[1];
        float v2 = (x1v[nt][2] * rs - mrs) * gg[2] + cc[2];
        float v3 = (x1v[nt][3] * rs - mrs) * gg[3] + cc[3];
        uint2_t pk;
        pk[0] = h2u(pkrtz(v0, v1));
        pk[1] = h2u(pkrtz(v2, v3));
        *(uint2_t*)&xl[wave][m * XLST + cob] = pk;
    }
    // no barrier: xl[wave] is wave-private; lgkmcnt orders write->read
    f16x8 xb0 = __builtin_bit_cast(f16x8, *(const uint4_t*)&xl[wave][m * XLST + quad * 8]);
    f16x8 xb1 = __builtin_bit_cast(f16x8, *(const uint4_t*)&xl[wave][m * XLST + 32 + quad * 8]);
#pragma unroll
    for (int pg = 0; pg < 8; ++pg) {
        f32x4 aA = {0.f,0.f,0.f,0.f}, aB = {0.f,0.f,0.f,0.f};
        f16x8 w3a0 = __builtin_bit_cast(f16x8, *(const uint4_t*)(w3t + (pg * 16 + m) * 64 + quad * 8));
        f16x8 w3a1 = __builtin_bit_cast(f16x8, *(const uint4_t*)(w3t + (pg * 16 + m) * 64 + 32 + quad * 8));
        f16x8 w3b0 = __builtin_bit_cast(f16x8, *(const uint4_t*)(w3t + (128 + pg * 16 + m) * 64 + quad * 8));
        f16x8 w3b1 = __builtin_bit_cast(f16x8, *(const uint4_t*)(w3t + (128 + pg * 16 + m) * 64 + 32 + quad * 8));
        __builtin_amdgcn_s_setprio(1);
        aA = __builtin_amdgcn_mfma_f32_16x16x32_f16(w3a0, xb0, aA, 0, 0, 0);
        aA = __builtin_amdgcn_mfma_f32_16x16x32_f16(w3a1, xb1, aA, 0, 0, 0);
        aB = __builtin_amdgcn_mfma_f32_16x16x32_f16(w3b0, xb0, aB, 0, 0, 0);
        aB = __builtin_amdgcn_mfma_f32_16x16x32_f16(w3b1, xb1, aB, 0, 0, 0);
        __builtin_amdgcn_s_setprio(0);
        int cb = pg * 16 + quad * 4;
        f32x4 bA = *(const f32x4*)(b3 + cb);
        f32x4 bB = *(const f32x4*)(b3 + 128 + cb);
        float p0 = (aA[0] + bA[0]) * (aB[0] + bB[0]);
        float p1 = (aA[1] + bA[1]) * (aB[1] + bB[1]);
        float p2 = (aA[2] + bA[2]) * (aB[2] + bB[2]);
        float p3 = (aA[3] + bA[3]) * (aB[3] + bB[3]);
        uint2_t pk;
        pk[0] = h2u(pkrtz(p0, p1));
        pk[1] = h2u(pkrtz(p2, p3));
        *(uint2_t*)&zt[wave][m * ZTST + cb] = pk;
    }
    // no barrier: zt[wave] is wave-private
    f32x4 acc4[4];
#pragma unroll
    for (int nt = 0; nt < 4; ++nt) { f32x4 z = {0.f,0.f,0.f,0.f}; acc4[nt] = z; }
    __builtin_amdgcn_s_setprio(1);
#pragma unroll
    for (int kh = 0; kh < 4; ++kh) {
        f16x8 zb = __builtin_bit_cast(f16x8, *(const uint4_t*)&zt[wave][m * ZTST + kh * 32 + quad * 8]);
#pragma unroll
        for (int nt = 0; nt < 4; ++nt) {
            f16x8 aw = __builtin_bit_cast(f16x8,
                *(const uint4_t*)(w4t + (nt * 16 + m) * 128 + kh * 32 + quad * 8));
            acc4[nt] = __builtin_amdgcn_mfma_f32_16x16x32_f16(aw, zb, acc4[nt], 0, 0, 0);
        }
    }
    __builtin_amdgcn_s_setprio(0);
#pragma unroll
    for (int nt = 0; nt < 4; ++nt) {
        int cob = nt * 16 + quad * 4;
        f32x4 bb = *(const f32x4*)(b4 + cob);
        f32x4 gm = *(const f32x4*)(gamma + cob);
        f32x4 o;
#pragma unroll
        for (int r = 0; r < 4; ++r)
            o[r] = x1v[nt][r] + (acc4[nt][r] + bb[r]) * gm[r];
        *(f32x4*)(out + (px0 + m) * 64 + cob) = o;
    }
}

// ---------- launch ----------
extern "C" void kernel_launch(void* const* d_in, const int* in_sizes, int n_in,
                              void* d_out, int out_size, void* d_ws, size_t ws_size,
                              hipStream_t stream) {
    (void)in_sizes; (void)n_in; (void)out_size; (void)ws_size;
    const float* x    = (const float*)d_in[0];
    const float* ln1g = (const float*)d_in[1];
    const float* ln1b = (const float*)d_in[2];
    const float* pw1w = (const float*)d_in[3];
    const float* pw1b = (const float*)d_in[4];
    const float* dww  = (const float*)d_in[5];
    const float* dwb  = (const float*)d_in[6];
    const float* scaw = (const float*)d_in[7];
    const float* scab = (const float*)d_in[8];
    const float* pw2w = (const float*)d_in[9];
    const float* pw2b = (const float*)d_in[10];
    const float* beta = (const float*)d_in[11];
    const float* ln2g = (const float*)d_in[12];
    const float* ln2b = (const float*)d_in[13];
    const float* pw3w = (const float*)d_in[14];
    const float* pw3b = (const float*)d_in[15];
    const float* pw4w = (const float*)d_in[16];
    const float* pw4b = (const float*)d_in[17];
    const float* gamma= (const float*)d_in[18];

    char* ws = (char*)d_ws;
    short* w1t = (short*)(ws + OFF_W1T);
    short* w2t = (short*)(ws + OFF_W2T);
    short* w3t = (short*)(ws + OFF_W3T);
    short* w4t = (short*)(ws + OFF_W4T);
    short* dwh = (short*)(ws + OFF_DWH);
    short* dbh = (short*)(ws + OFF_DBH);
    float* watt = (float*)(ws + OFF_WATT);
    float* gpart = (float*)(ws + OFF_GPART);
    short* t   = (short*)(ws + OFF_T);
    float* out = (float*)d_out;

    k_prep<<<64, 256, 0, stream>>>(pw1w, pw2w, pw3w, pw4w, dww, dwb,
                                   w1t, w2t, w3t, w4t, dwh, dbh);
    k_a<<<16384, 256, 0, stream>>>(x, ln1g, ln1b, w1t, pw1b, dwh, dbh, t, gpart);
    k_sca<<<8, 256, 0, stream>>>(gpart, scaw, scab, watt);
    k_b<<<8192, 256, 0, stream>>>(t, watt, w2t, pw2b, x, beta, ln2g, ln2b,
                                  w3t, pw3b, w4t, pw4b, gamma, out);
}

// Round 9
// 736.913 us; speedup vs baseline: 1.3879x; 1.3879x over previous
//
#include <hip/hip_runtime.h>

// ---------- types / helpers ----------
typedef __attribute__((ext_vector_type(8))) _Float16 f16x8;
typedef __attribute__((ext_vector_type(2))) _Float16 h2;
typedef __attribute__((ext_vector_type(4))) float f32x4;
typedef __attribute__((ext_vector_type(2))) float f32x2;
typedef __attribute__((ext_vector_type(4))) unsigned uint4_t;
typedef __attribute__((ext_vector_type(2))) unsigned uint2_t;

__device__ __forceinline__ h2 pkrtz(float a, float b) {
    return __builtin_bit_cast(h2, __builtin_amdgcn_cvt_pkrtz(a, b));   // v_cvt_pkrtz_f16_f32
}
__device__ __forceinline__ unsigned h2u(h2 v) { return __builtin_bit_cast(unsigned, v); }
__device__ __forceinline__ h2 u2h(unsigned u) { return __builtin_bit_cast(h2, u); }
__device__ __forceinline__ short f2h(float f) { return __builtin_bit_cast(short, (_Float16)f); }

// ws layout (bytes)
#define OFF_W1T 0L            // 32768
#define OFF_W2T 32768L        // 16384
#define OFF_W3T 49152L        // 32768
#define OFF_W4T 81920L        // 16384
#define OFF_DWH 98304L        // 4608
#define OFF_DBH 102912L       // 512
#define OFF_WATT 103424L      // 4096
#define OFF_GPART 107520L     // 2048*128*4 = 1048576
#define OFF_T 1156096L        // 524288*128*2 = 134217728

// ---------- K0: weight transpose + fp16 cast ----------
__global__ __launch_bounds__(256) void k_prep(
    const float* __restrict__ w1, const float* __restrict__ w2,
    const float* __restrict__ w3, const float* __restrict__ w4,
    const float* __restrict__ dww, const float* __restrict__ dwb,
    short* __restrict__ w1t, short* __restrict__ w2t,
    short* __restrict__ w3t, short* __restrict__ w4t,
    short* __restrict__ dwh, short* __restrict__ dbh)
{
    int id = blockIdx.x * 256 + threadIdx.x;
    if (id < 64 * 256) {
        int ci = id >> 8, co = id & 255;
        w1t[co * 64 + ci] = f2h(w1[id]);
        w3t[co * 64 + ci] = f2h(w3[id]);
    }
    if (id < 128 * 64) {
        int ci = id >> 6, co = id & 63;
        w2t[co * 128 + ci] = f2h(w2[id]);
        w4t[co * 128 + ci] = f2h(w4[id]);
    }
    if (id < 9 * 256) dwh[id] = f2h(dww[id]);
    if (id < 256)     dbh[id] = f2h(dwb[id]);
}

// ---------- K_A: LN1 + pw1(MFMA) + dw3x3 + gate ----------
// LDS: u tile [100 rows][128 shorts], XOR-swizzled (byte ^= (row&7)<<4).
// 25600 B -> 6 blocks/CU.  (round-5 measured form)
__global__ __launch_bounds__(256) void k_a(
    const float* __restrict__ x, const float* __restrict__ ln1g, const float* __restrict__ ln1b,
    const short* __restrict__ w1t, const float* __restrict__ b1,
    const short* __restrict__ dwh, const short* __restrict__ dbh,
    short* __restrict__ t)
{
    __shared__ short uh[100 * 128];   // 25600 B
    const int blk = blockIdx.x;
    const int cs  = blk & 1;
    const int txy = blk >> 1;
    const int tx  = txy & 31;
    const int ty  = (txy >> 5) & 31;
    const int b   = txy >> 10;
    const int tid = threadIdx.x;
    const int lane = tid & 63;
    const int wave = tid >> 6;
    const int m    = lane & 15;
    const int quad = lane >> 4;

    // ---- phase 1: two pixel-slots per wave (pA = wave*16+m, pB = pA+64)
    const int pA = wave * 16 + m;
    const int pB = pA + 64;
    const int hyA = (pA * 205) >> 11, hxA = pA - hyA * 10;
    const int hyB = (pB * 205) >> 11, hxB = pB - hyB * 10;
    const int gyA = ty * 8 + hyA - 1, gxA = tx * 8 + hxA - 1;
    const int gyB = ty * 8 + hyB - 1, gxB = tx * 8 + hxB - 1;
    const bool imgA = gyA >= 0 && gyA < 256 && gxA >= 0 && gxA < 256;  // pA<100 always
    const bool imgB = (pB < 100) && gyB >= 0 && gyB < 256 && gxB >= 0 && gxB < 256;
    const bool aliveB = (wave < 3);   // wave3's B slot (p>=112) fully dead

    f32x4 fA[4], fB[4];
#pragma unroll
    for (int i = 0; i < 4; ++i) {
        fA[i] = (f32x4){0.f,0.f,0.f,0.f};
        fB[i] = (f32x4){0.f,0.f,0.f,0.f};
    }
    if (imgA) {
        const float* xr = x + ((long)((b * 256 + gyA) * 256 + gxA)) * 64 + quad * 8;
        fA[0] = *(const f32x4*)(xr);      fA[1] = *(const f32x4*)(xr + 4);
        fA[2] = *(const f32x4*)(xr + 32); fA[3] = *(const f32x4*)(xr + 36);
    }
    if (imgB) {
        const float* xr = x + ((long)((b * 256 + gyB) * 256 + gxB)) * 64 + quad * 8;
        fB[0] = *(const f32x4*)(xr);      fB[1] = *(const f32x4*)(xr + 4);
        fB[2] = *(const f32x4*)(xr + 32); fB[3] = *(const f32x4*)(xr + 36);
    }

    // LN affine params loaded once, shared by both slots
    f32x4 g0 = *(const f32x4*)(ln1g + quad * 8);
    f32x4 g1 = *(const f32x4*)(ln1g + quad * 8 + 4);
    f32x4 g2 = *(const f32x4*)(ln1g + 32 + quad * 8);
    f32x4 g3 = *(const f32x4*)(ln1g + 32 + quad * 8 + 4);
    f32x4 c0 = *(const f32x4*)(ln1b + quad * 8);
    f32x4 c1 = *(const f32x4*)(ln1b + quad * 8 + 4);
    f32x4 c2 = *(const f32x4*)(ln1b + 32 + quad * 8);
    f32x4 c3 = *(const f32x4*)(ln1b + 32 + quad * 8 + 4);

    f16x8 a0A = {0,0,0,0,0,0,0,0}, a1A = {0,0,0,0,0,0,0,0};
    f16x8 a0B = {0,0,0,0,0,0,0,0}, a1B = {0,0,0,0,0,0,0,0};

    if (imgA) {
        float s  = 0.f, s2 = 0.f;
#pragma unroll
        for (int i = 0; i < 4; ++i)
#pragma unroll
            for (int r = 0; r < 4; ++r) { s += fA[i][r]; s2 += fA[i][r] * fA[i][r]; }
        s  += __shfl_xor(s, 16);  s  += __shfl_xor(s, 32);
        s2 += __shfl_xor(s2, 16); s2 += __shfl_xor(s2, 32);
        float mean = s * 0.015625f;
        float var  = s2 * 0.015625f - mean * mean;
        float rs   = rsqrtf(var + 1e-6f);
        float mrs  = mean * rs;
        uint4_t ra, rb;
#define LNP(va,vb,ga,gb,ca,cb) h2u(pkrtz(((va)*rs - mrs)*(ga) + (ca), ((vb)*rs - mrs)*(gb) + (cb)))
        ra[0] = LNP(fA[0][0],fA[0][1],g0[0],g0[1],c0[0],c0[1]);
        ra[1] = LNP(fA[0][2],fA[0][3],g0[2],g0[3],c0[2],c0[3]);
        ra[2] = LNP(fA[1][0],fA[1][1],g1[0],g1[1],c1[0],c1[1]);
        ra[3] = LNP(fA[1][2],fA[1][3],g1[2],g1[3],c1[2],c1[3]);
        rb[0] = LNP(fA[2][0],fA[2][1],g2[0],g2[1],c2[0],c2[1]);
        rb[1] = LNP(fA[2][2],fA[2][3],g2[2],g2[3],c2[2],c2[3]);
        rb[2] = LNP(fA[3][0],fA[3][1],g3[0],g3[1],c3[0],c3[1]);
        rb[3] = LNP(fA[3][2],fA[3][3],g3[2],g3[3],c3[2],c3[3]);
        a0A = __builtin_bit_cast(f16x8, ra);
        a1A = __builtin_bit_cast(f16x8, rb);
    }
    if (imgB) {
        float s  = 0.f, s2 = 0.f;
#pragma unroll
        for (int i = 0; i < 4; ++i)
#pragma unroll
            for (int r = 0; r < 4; ++r) { s += fB[i][r]; s2 += fB[i][r] * fB[i][r]; }
        s  += __shfl_xor(s, 16);  s  += __shfl_xor(s, 32);
        s2 += __shfl_xor(s2, 16); s2 += __shfl_xor(s2, 32);
        float mean = s * 0.015625f;
        float var  = s2 * 0.015625f - mean * mean;
        float rs   = rsqrtf(var + 1e-6f);
        float mrs  = mean * rs;
        uint4_t ra, rb;
        ra[0] = LNP(fB[0][0],fB[0][1],g0[0],g0[1],c0[0],c0[1]);
        ra[1] = LNP(fB[0][2],fB[0][3],g0[2],g0[3],c0[2],c0[3]);
        ra[2] = LNP(fB[1][0],fB[1][1],g1[0],g1[1],c1[0],c1[1]);
        ra[3] = LNP(fB[1][2],fB[1][3],g1[2],g1[3],c1[2],c1[3]);
        rb[0] = LNP(fB[2][0],fB[2][1],g2[0],g2[1],c2[0],c2[1]);
        rb[1] = LNP(fB[2][2],fB[2][3],g2[2],g2[3],c2[2],c2[3]);
        rb[2] = LNP(fB[3][0],fB[3][1],g3[0],g3[1],c3[0],c3[1]);
        rb[3] = LNP(fB[3][2],fB[3][3],g3[2],g3[3],c3[2],c3[3]);
#undef LNP
        a0B = __builtin_bit_cast(f16x8, ra);
        a1B = __builtin_bit_cast(f16x8, rb);
    }

    // MFMA: each w1t/b1 fragment loaded once, feeds both slots
    char* uhc = (char*)uh;
#pragma unroll
    for (int cot = 0; cot < 8; ++cot) {
        const int cob = (cot < 4) ? (cs * 64 + cot * 16) : (128 + cs * 64 + (cot - 4) * 16);
        const f16x8 wlo = __builtin_bit_cast(f16x8, *(const uint4_t*)(w1t + (cob + m) * 64 + quad * 8));
        const f16x8 whi = __builtin_bit_cast(f16x8, *(const uint4_t*)(w1t + (cob + m) * 64 + 32 + quad * 8));
        const f32x4 bv = *(const f32x4*)(b1 + cob + quad * 4);
        {
            f32x4 acc = {0.f,0.f,0.f,0.f};
            acc = __builtin_amdgcn_mfma_f32_16x16x32_f16(wlo, a0A, acc, 0, 0, 0);
            acc = __builtin_amdgcn_mfma_f32_16x16x32_f16(whi, a1A, acc, 0, 0, 0);
            uint2_t pk;
            pk[0] = imgA ? h2u(pkrtz(acc[0] + bv[0], acc[1] + bv[1])) : 0u;
            pk[1] = imgA ? h2u(pkrtz(acc[2] + bv[2], acc[3] + bv[3])) : 0u;
            int off = (pA * 256 + cot * 32 + quad * 8) ^ ((pA & 7) << 4);
            *(uint2_t*)(uhc + off) = pk;
        }
        if (aliveB) {
            f32x4 acc = {0.f,0.f,0.f,0.f};
            acc = __builtin_amdgcn_mfma_f32_16x16x32_f16(wlo, a0B, acc, 0, 0, 0);
            acc = __builtin_amdgcn_mfma_f32_16x16x32_f16(whi, a1B, acc, 0, 0, 0);
            if (pB < 100) {
                uint2_t pk;
                pk[0] = imgB ? h2u(pkrtz(acc[0] + bv[0], acc[1] + bv[1])) : 0u;
                pk[1] = imgB ? h2u(pkrtz(acc[2] + bv[2], acc[3] + bv[3])) : 0u;
                int off = (pB * 256 + cot * 32 + quad * 8) ^ ((pB & 7) << 4);
                *(uint2_t*)(uhc + off) = pk;
            }
        }
    }
    __syncthreads();

    // ---- phase 2: dw3x3 + gate, packed fp16 ----
    const int y = lane >> 3, xx = lane & 7;
    const int cq = wave;
    const int gc0 = cs * 64 + cq * 16;
    const long gpx = ((long)(b * 256 + ty * 8 + y) * 256) + tx * 8 + xx;

    h2 A1[8], A2[8];
#pragma unroll
    for (int j = 0; j < 8; ++j) {
        A1[j] = u2h(0u);
        A2[j] = u2h(0u);
    }
#pragma unroll
    for (int dy = 0; dy < 3; ++dy)
#pragma unroll
    for (int dx = 0; dx < 3; ++dx) {
        int h = (y + dy) * 10 + (xx + dx);
        int sw = (h & 7) << 4;
        int b0 = h * 256 + cq * 32;
        uint4_t u1l  = *(const uint4_t*)(uhc + ((b0)       ^ sw));
        uint4_t u1h  = *(const uint4_t*)(uhc + ((b0 + 16)  ^ sw));
        uint4_t u2l  = *(const uint4_t*)(uhc + ((b0 + 128) ^ sw));
        uint4_t u2hv = *(const uint4_t*)(uhc + ((b0 + 144) ^ sw));
        const uint4_t* wp = (const uint4_t*)(dwh + (dy * 3 + dx) * 256 + gc0);
        const uint4_t* vp = (const uint4_t*)(dwh + (dy * 3 + dx) * 256 + 128 + gc0);
        uint4_t w1l = wp[0], w1h = wp[1];
        uint4_t w2l = vp[0], w2h = vp[1];
#pragma unroll
        for (int j = 0; j < 4; ++j) {
            A1[j]     += u2h(u1l[j])  * u2h(w1l[j]);
            A1[j + 4] += u2h(u1h[j])  * u2h(w1h[j]);
            A2[j]     += u2h(u2l[j])  * u2h(w2l[j]);
            A2[j + 4] += u2h(u2hv[j]) * u2h(w2h[j]);
        }
    }
    const uint4_t* bp1 = (const uint4_t*)(dbh + gc0);
    const uint4_t* bp2 = (const uint4_t*)(dbh + 128 + gc0);
    uint4_t b1l = bp1[0], b1h = bp1[1];
    uint4_t b2l = bp2[0], b2h = bp2[1];
    uint4_t s0, s1;
#pragma unroll
    for (int j = 0; j < 4; ++j) {
        h2 t0 = (A1[j]     + u2h(b1l[j])) * (A2[j]     + u2h(b2l[j]));
        h2 t1 = (A1[j + 4] + u2h(b1h[j])) * (A2[j + 4] + u2h(b2h[j]));
        s0[j] = h2u(t0);
        s1[j] = h2u(t1);
    }
    *(uint4_t*)(t + gpx * 128 + gc0)     = s0;
    *(uint4_t*)(t + gpx * 128 + gc0 + 8) = s1;
}

// ---------- K_R: GAP over t (b128 loads, 2048 blocks) ----------
__global__ __launch_bounds__(256) void k_red(
    const short* __restrict__ t, float* __restrict__ gpart)
{
    __shared__ float red[16][16][8];   // [pr][cg][j]  8 KB
    const int blk = blockIdx.x;        // 2048 = 8 batch x 256 slices
    const int tid = threadIdx.x;
    const int cg = tid & 15;
    const int pr = tid >> 4;
    const short* tb = t + (long)blk * 256 * 128 + cg * 8;
    float a0=0,a1=0,a2=0,a3=0,a4=0,a5=0,a6=0,a7=0;
#pragma unroll 4
    for (int it = 0; it < 16; ++it) {
        uint4_t u = *(const uint4_t*)(tb + (long)(it * 16 + pr) * 128);
        h2 v0=u2h(u[0]), v1=u2h(u[1]), v2=u2h(u[2]), v3=u2h(u[3]);
        a0 += (float)v0[0]; a1 += (float)v0[1]; a2 += (float)v1[0]; a3 += (float)v1[1];
        a4 += (float)v2[0]; a5 += (float)v2[1]; a6 += (float)v3[0]; a7 += (float)v3[1];
    }
    red[pr][cg][0]=a0; red[pr][cg][1]=a1; red[pr][cg][2]=a2; red[pr][cg][3]=a3;
    red[pr][cg][4]=a4; red[pr][cg][5]=a5; red[pr][cg][6]=a6; red[pr][cg][7]=a7;
    __syncthreads();
    if (tid < 128) {
        int g = tid >> 3, j = tid & 7;
        float s = 0.f;
#pragma unroll
        for (int r = 0; r < 16; ++r) s += red[r][g][j];
        gpart[(long)blk * 128 + tid] = s;
    }
}

// ---------- K_S: final GAP + SCA (one block per batch) ----------
__global__ __launch_bounds__(256) void k_sca2(
    const float* __restrict__ gpart, const float* __restrict__ scaw,
    const float* __restrict__ scab, float* __restrict__ watt)
{
    __shared__ float gl[256];
    __shared__ float gn[128];
    const int b = blockIdx.x;
    const int tid = threadIdx.x;
    const int c = tid & 127, half = tid >> 7;
    float s = 0.f;
    const float* gp = gpart + (long)b * 256 * 128 + c;
    for (int i = half; i < 256; i += 2) s += gp[(long)i * 128];
    gl[half * 128 + c] = s;
    __syncthreads();
    if (tid < 128) gn[c] = (gl[c] + gl[128 + c]) * (1.0f / 65536.0f);
    __syncthreads();
    if (tid < 128) {
        float acc = scab[c];
        for (int ci = 0; ci < 128; ++ci) acc += gn[ci] * scaw[ci * 128 + c];
        watt[b * 128 + c] = acc;
    }
}

// ---------- K_B: pw2 + residual + LN2 + pw3 + gate + pw4 + residual ----------
// TWO pixel-groups per wave (A at px, B at px+64): every weight fragment is
// loaded once and feeds two MFMAs (halves L1/L2 weight traffic, doubles
// per-wave ILP). Registers deliberately spend the free headroom of the
// 65..128 VGPR occupancy step. xl/zt are per-(wave,group)-private slabs:
// no __syncthreads anywhere (lgkmcnt orders write->read within a wave).
#define XLST 72
#define ZTST 136
__global__ __launch_bounds__(256) void k_b(
    const short* __restrict__ t, const float* __restrict__ watt,
    const short* __restrict__ w2t, const float* __restrict__ b2,
    const float* __restrict__ x, const float* __restrict__ beta,
    const float* __restrict__ ln2g, const float* __restrict__ ln2b,
    const short* __restrict__ w3t, const float* __restrict__ b3,
    const short* __restrict__ w4t, const float* __restrict__ b4,
    const float* __restrict__ gamma, float* __restrict__ out)
{
    __shared__ short xl[8][16 * XLST];   // 18432 B
    __shared__ short zt[8][16 * ZTST];   // 34816 B
    const int lane = threadIdx.x & 63;
    const int wave = threadIdx.x >> 6;
    const int m = lane & 15, quad = lane >> 4;
    const long pxA = (long)blockIdx.x * 128 + wave * 16 + m;
    const long pxB = pxA + 64;
    const int b = (int)(((long)blockIdx.x * 128) >> 16);
    const float* wa = watt + b * 128;
    const int sA = wave, sB = wave + 4;

    // residual x loads first (both groups): latency hides under t-load + pw2
    f32x4 xvA[4], xvB[4];
#pragma unroll
    for (int nt = 0; nt < 4; ++nt) {
        xvA[nt] = *(const f32x4*)(x + pxA * 64 + nt * 16 + quad * 4);
        xvB[nt] = *(const f32x4*)(x + pxB * 64 + nt * 16 + quad * 4);
    }

    const short* trA = t + pxA * 128;
    const short* trB = t + pxB * 128;
    f32x4 acc2A[4], acc2B[4];
#pragma unroll
    for (int nt = 0; nt < 4; ++nt) {
        acc2A[nt] = (f32x4){0.f,0.f,0.f,0.f};
        acc2B[nt] = (f32x4){0.f,0.f,0.f,0.f};
    }
#pragma unroll
    for (int kh = 0; kh < 4; ++kh) {
        uint4_t tA = *(const uint4_t*)(trA + kh * 32 + quad * 8);
        uint4_t tB = *(const uint4_t*)(trB + kh * 32 + quad * 8);
        f32x4 w0  = *(const f32x4*)(wa + kh * 32 + quad * 8);
        f32x4 w1v = *(const f32x4*)(wa + kh * 32 + quad * 8 + 4);
        h2 s01 = pkrtz(w0[0], w0[1]),  s23 = pkrtz(w0[2], w0[3]);
        h2 s45 = pkrtz(w1v[0], w1v[1]), s67 = pkrtz(w1v[2], w1v[3]);
        uint4_t oA, oB;
        oA[0] = h2u(u2h(tA[0]) * s01); oA[1] = h2u(u2h(tA[1]) * s23);
        oA[2] = h2u(u2h(tA[2]) * s45); oA[3] = h2u(u2h(tA[3]) * s67);
        oB[0] = h2u(u2h(tB[0]) * s01); oB[1] = h2u(u2h(tB[1]) * s23);
        oB[2] = h2u(u2h(tB[2]) * s45); oB[3] = h2u(u2h(tB[3]) * s67);
        f16x8 bfrA = __builtin_bit_cast(f16x8, oA);
        f16x8 bfrB = __builtin_bit_cast(f16x8, oB);
#pragma unroll
        for (int nt = 0; nt < 4; ++nt) {
            f16x8 aw = __builtin_bit_cast(f16x8,
                *(const uint4_t*)(w2t + (nt * 16 + m) * 128 + kh * 32 + quad * 8));
            acc2A[nt] = __builtin_amdgcn_mfma_f32_16x16x32_f16(aw, bfrA, acc2A[nt], 0, 0, 0);
            acc2B[nt] = __builtin_amdgcn_mfma_f32_16x16x32_f16(aw, bfrB, acc2B[nt], 0, 0, 0);
        }
    }
    float x1A[4][4], x1B[4][4];
#pragma unroll
    for (int nt = 0; nt < 4; ++nt) {
        int cob = nt * 16 + quad * 4;
        f32x4 bb = *(const f32x4*)(b2 + cob);
        f32x4 be = *(const f32x4*)(beta + cob);
#pragma unroll
        for (int r = 0; r < 4; ++r) {
            x1A[nt][r] = xvA[nt][r] + (acc2A[nt][r] + bb[r]) * be[r];
            x1B[nt][r] = xvB[nt][r] + (acc2B[nt][r] + bb[r]) * be[r];
        }
    }
    // LN2 for both groups
    float sa = 0.f, s2a = 0.f, sb = 0.f, s2b = 0.f;
#pragma unroll
    for (int nt = 0; nt < 4; ++nt)
#pragma unroll
        for (int r = 0; r < 4; ++r) {
            sa += x1A[nt][r]; s2a += x1A[nt][r] * x1A[nt][r];
            sb += x1B[nt][r]; s2b += x1B[nt][r] * x1B[nt][r];
        }
    sa  += __shfl_xor(sa, 16);  sa  += __shfl_xor(sa, 32);
    s2a += __shfl_xor(s2a, 16); s2a += __shfl_xor(s2a, 32);
    sb  += __shfl_xor(sb, 16);  sb  += __shfl_xor(sb, 32);
    s2b += __shfl_xor(s2b, 16); s2b += __shfl_xor(s2b, 32);
    float meanA = sa * 0.015625f;
    float varA  = s2a * 0.015625f - meanA * meanA;
    float rsA   = rsqrtf(varA + 1e-6f);
    float mrsA  = meanA * rsA;
    float meanB = sb * 0.015625f;
    float varB  = s2b * 0.015625f - meanB * meanB;
    float rsB   = rsqrtf(varB + 1e-6f);
    float mrsB  = meanB * rsB;
#pragma unroll
    for (int nt = 0; nt < 4; ++nt) {
        int cob = nt * 16 + quad * 4;
        f32x4 gg = *(const f32x4*)(ln2g + cob);
        f32x4 cc = *(const f32x4*)(ln2b + cob);
        uint2_t pkA, pkB;
        pkA[0] = h2u(pkrtz((x1A[nt][0] * rsA - mrsA) * gg[0] + cc[0],
                           (x1A[nt][1] * rsA - mrsA) * gg[1] + cc[1]));
        pkA[1] = h2u(pkrtz((x1A[nt][2] * rsA - mrsA) * gg[2] + cc[2],
                           (x1A[nt][3] * rsA - mrsA) * gg[3] + cc[3]));
        pkB[0] = h2u(pkrtz((x1B[nt][0] * rsB - mrsB) * gg[0] + cc[0],
                           (x1B[nt][1] * rsB - mrsB) * gg[1] + cc[1]));
        pkB[1] = h2u(pkrtz((x1B[nt][2] * rsB - mrsB) * gg[2] + cc[2],
                           (x1B[nt][3] * rsB - mrsB) * gg[3] + cc[3]));
        *(uint2_t*)&xl[sA][m * XLST + cob] = pkA;
        *(uint2_t*)&xl[sB][m * XLST + cob] = pkB;
    }
    // no barrier: xl slabs are wave-private
    f16x8 xbA0 = __builtin_bit_cast(f16x8, *(const uint4_t*)&xl[sA][m * XLST + quad * 8]);
    f16x8 xbA1 = __builtin_bit_cast(f16x8, *(const uint4_t*)&xl[sA][m * XLST + 32 + quad * 8]);
    f16x8 xbB0 = __builtin_bit_cast(f16x8, *(const uint4_t*)&xl[sB][m * XLST + quad * 8]);
    f16x8 xbB1 = __builtin_bit_cast(f16x8, *(const uint4_t*)&xl[sB][m * XLST + 32 + quad * 8]);
#pragma unroll
    for (int pg = 0; pg < 8; ++pg) {
        f16x8 w3a0 = __builtin_bit_cast(f16x8, *(const uint4_t*)(w3t + (pg * 16 + m) * 64 + quad * 8));
        f16x8 w3a1 = __builtin_bit_cast(f16x8, *(const uint4_t*)(w3t + (pg * 16 + m) * 64 + 32 + quad * 8));
        f16x8 w3b0 = __builtin_bit_cast(f16x8, *(const uint4_t*)(w3t + (128 + pg * 16 + m) * 64 + quad * 8));
        f16x8 w3b1 = __builtin_bit_cast(f16x8, *(const uint4_t*)(w3t + (128 + pg * 16 + m) * 64 + 32 + quad * 8));
        f32x4 aAA = {0.f,0.f,0.f,0.f}, aBA = {0.f,0.f,0.f,0.f};
        f32x4 aAB = {0.f,0.f,0.f,0.f}, aBB = {0.f,0.f,0.f,0.f};
        aAA = __builtin_amdgcn_mfma_f32_16x16x32_f16(w3a0, xbA0, aAA, 0, 0, 0);
        aAA = __builtin_amdgcn_mfma_f32_16x16x32_f16(w3a1, xbA1, aAA, 0, 0, 0);
        aBA = __builtin_amdgcn_mfma_f32_16x16x32_f16(w3b0, xbA0, aBA, 0, 0, 0);
        aBA = __builtin_amdgcn_mfma_f32_16x16x32_f16(w3b1, xbA1, aBA, 0, 0, 0);
        aAB = __builtin_amdgcn_mfma_f32_16x16x32_f16(w3a0, xbB0, aAB, 0, 0, 0);
        aAB = __builtin_amdgcn_mfma_f32_16x16x32_f16(w3a1, xbB1, aAB, 0, 0, 0);
        aBB = __builtin_amdgcn_mfma_f32_16x16x32_f16(w3b0, xbB0, aBB, 0, 0, 0);
        aBB = __builtin_amdgcn_mfma_f32_16x16x32_f16(w3b1, xbB1, aBB, 0, 0, 0);
        int cb = pg * 16 + quad * 4;
        f32x4 bA_ = *(const f32x4*)(b3 + cb);
        f32x4 bB_ = *(const f32x4*)(b3 + 128 + cb);
        uint2_t pkA, pkB;
        pkA[0] = h2u(pkrtz((aAA[0] + bA_[0]) * (aBA[0] + bB_[0]),
                           (aAA[1] + bA_[1]) * (aBA[1] + bB_[1])));
        pkA[1] = h2u(pkrtz((aAA[2] + bA_[2]) * (aBA[2] + bB_[2]),
                           (aAA[3] + bA_[3]) * (aBA[3] + bB_[3])));
        pkB[0] = h2u(pkrtz((aAB[0] + bA_[0]) * (aBB[0] + bB_[0]),
                           (aAB[1] + bA_[1]) * (aBB[1] + bB_[1])));
        pkB[1] = h2u(pkrtz((aAB[2] + bA_[2]) * (aBB[2] + bB_[2]),
                           (aAB[3] + bA_[3]) * (aBB[3] + bB_[3])));
        *(uint2_t*)&zt[sA][m * ZTST + cb] = pkA;
        *(uint2_t*)&zt[sB][m * ZTST + cb] = pkB;
    }
    // no barrier: zt slabs are wave-private
    f32x4 acc4A[4], acc4B[4];
#pragma unroll
    for (int nt = 0; nt < 4; ++nt) {
        acc4A[nt] = (f32x4){0.f,0.f,0.f,0.f};
        acc4B[nt] = (f32x4){0.f,0.f,0.f,0.f};
    }
#pragma unroll
    for (int kh = 0; kh < 4; ++kh) {
        f16x8 zbA = __builtin_bit_cast(f16x8, *(const uint4_t*)&zt[sA][m * ZTST + kh * 32 + quad * 8]);
        f16x8 zbB = __builtin_bit_cast(f16x8, *(const uint4_t*)&zt[sB][m * ZTST + kh * 32 + quad * 8]);
#pragma unroll
        for (int nt = 0; nt < 4; ++nt) {
            f16x8 aw = __builtin_bit_cast(f16x8,
                *(const uint4_t*)(w4t + (nt * 16 + m) * 128 + kh * 32 + quad * 8));
            acc4A[nt] = __builtin_amdgcn_mfma_f32_16x16x32_f16(aw, zbA, acc4A[nt], 0, 0, 0);
            acc4B[nt] = __builtin_amdgcn_mfma_f32_16x16x32_f16(aw, zbB, acc4B[nt], 0, 0, 0);
        }
    }
#pragma unroll
    for (int nt = 0; nt < 4; ++nt) {
        int cob = nt * 16 + quad * 4;
        f32x4 bb = *(const f32x4*)(b4 + cob);
        f32x4 gm = *(const f32x4*)(gamma + cob);
        f32x4 oA, oB;
#pragma unroll
        for (int r = 0; r < 4; ++r) {
            oA[r] = x1A[nt][r] + (acc4A[nt][r] + bb[r]) * gm[r];
            oB[r] = x1B[nt][r] + (acc4B[nt][r] + bb[r]) * gm[r];
        }
        *(f32x4*)(out + pxA * 64 + cob) = oA;
        *(f32x4*)(out + pxB * 64 + cob) = oB;
    }
}

// ---------- launch ----------
extern "C" void kernel_launch(void* const* d_in, const int* in_sizes, int n_in,
                              void* d_out, int out_size, void* d_ws, size_t ws_size,
                              hipStream_t stream) {
    (void)in_sizes; (void)n_in; (void)out_size; (void)ws_size;
    const float* x    = (const float*)d_in[0];
    const float* ln1g = (const float*)d_in[1];
    const float* ln1b = (const float*)d_in[2];
    const float* pw1w = (const float*)d_in[3];
    const float* pw1b = (const float*)d_in[4];
    const float* dww  = (const float*)d_in[5];
    const float* dwb  = (const float*)d_in[6];
    const float* scaw = (const float*)d_in[7];
    const float* scab = (const float*)d_in[8];
    const float* pw2w = (const float*)d_in[9];
    const float* pw2b = (const float*)d_in[10];
    const float* beta = (const float*)d_in[11];
    const float* ln2g = (const float*)d_in[12];
    const float* ln2b = (const float*)d_in[13];
    const float* pw3w = (const float*)d_in[14];
    const float* pw3b = (const float*)d_in[15];
    const float* pw4w = (const float*)d_in[16];
    const float* pw4b = (const float*)d_in[17];
    const float* gamma= (const float*)d_in[18];

    char* ws = (char*)d_ws;
    short* w1t = (short*)(ws + OFF_W1T);
    short* w2t = (short*)(ws + OFF_W2T);
    short* w3t = (short*)(ws + OFF_W3T);
    short* w4t = (short*)(ws + OFF_W4T);
    short* dwh = (short*)(ws + OFF_DWH);
    short* dbh = (short*)(ws + OFF_DBH);
    float* watt = (float*)(ws + OFF_WATT);
    float* gpart = (float*)(ws + OFF_GPART);
    short* t   = (short*)(ws + OFF_T);
    float* out = (float*)d_out;

    k_prep<<<64, 256, 0, stream>>>(pw1w, pw2w, pw3w, pw4w, dww, dwb,
                                   w1t, w2t, w3t, w4t, dwh, dbh);
    k_a<<<16384, 256, 0, stream>>>(x, ln1g, ln1b, w1t, pw1b, dwh, dbh, t);
    k_red<<<2048, 256, 0, stream>>>(t, gpart);
    k_sca2<<<8, 256, 0, stream>>>(gpart, scaw, scab, watt);
    k_b<<<4096, 256, 0, stream>>>(t, watt, w2t, pw2b, x, beta, ln2g, ln2b,
                                  w3t, pw3b, w4t, pw4b, gamma, out);
}

// Round 10
// 697.374 us; speedup vs baseline: 1.4666x; 1.0567x over previous
//
#include <hip/hip_runtime.h>

// ---------- types / helpers ----------
typedef __attribute__((ext_vector_type(8))) _Float16 f16x8;
typedef __attribute__((ext_vector_type(2))) _Float16 h2;
typedef __attribute__((ext_vector_type(4))) float f32x4;
typedef __attribute__((ext_vector_type(2))) float f32x2;
typedef __attribute__((ext_vector_type(4))) unsigned uint4_t;
typedef __attribute__((ext_vector_type(2))) unsigned uint2_t;

__device__ __forceinline__ h2 pkrtz(float a, float b) {
    return __builtin_bit_cast(h2, __builtin_amdgcn_cvt_pkrtz(a, b));   // v_cvt_pkrtz_f16_f32
}
__device__ __forceinline__ unsigned h2u(h2 v) { return __builtin_bit_cast(unsigned, v); }
__device__ __forceinline__ h2 u2h(unsigned u) { return __builtin_bit_cast(h2, u); }
__device__ __forceinline__ short f2h(float f) { return __builtin_bit_cast(short, (_Float16)f); }

// ws layout (bytes)
#define OFF_W1T 0L            // 32768
#define OFF_W2T 32768L        // 16384
#define OFF_W3T 49152L        // 32768
#define OFF_W4T 81920L        // 16384
#define OFF_DWH 98304L        // 4608
#define OFF_DBH 102912L       // 512
#define OFF_WATT 103424L      // 4096
#define OFF_GPART 107520L     // 16384*64*4 = 4194304
#define OFF_GPART2 4301824L   // 64*128*4 = 32768
#define OFF_T 4334592L        // 524288*128*2 = 134217728

// ---------- K0: weight transpose + fp16 cast ----------
__global__ __launch_bounds__(256) void k_prep(
    const float* __restrict__ w1, const float* __restrict__ w2,
    const float* __restrict__ w3, const float* __restrict__ w4,
    const float* __restrict__ dww, const float* __restrict__ dwb,
    short* __restrict__ w1t, short* __restrict__ w2t,
    short* __restrict__ w3t, short* __restrict__ w4t,
    short* __restrict__ dwh, short* __restrict__ dbh)
{
    int id = blockIdx.x * 256 + threadIdx.x;
    if (id < 64 * 256) {
        int ci = id >> 8, co = id & 255;
        w1t[co * 64 + ci] = f2h(w1[id]);
        w3t[co * 64 + ci] = f2h(w3[id]);
    }
    if (id < 128 * 64) {
        int ci = id >> 6, co = id & 63;
        w2t[co * 128 + ci] = f2h(w2[id]);
        w4t[co * 128 + ci] = f2h(w4[id]);
    }
    if (id < 9 * 256) dwh[id] = f2h(dww[id]);
    if (id < 256)     dbh[id] = f2h(dwb[id]);
}

// ---------- K_A: LN1 + pw1(MFMA) + dw3x3 + gate + GAP partials ----------
// LDS: u tile [100 rows][128 shorts], XOR-swizzled (byte ^= (row&7)<<4).
// 25600 B -> 6 blocks/CU.  GAP partials via packed-f16 butterfly (validated
// round 6: absmax unchanged), so t never needs a second full HBM read.
__global__ __launch_bounds__(256) void k_a(
    const float* __restrict__ x, const float* __restrict__ ln1g, const float* __restrict__ ln1b,
    const short* __restrict__ w1t, const float* __restrict__ b1,
    const short* __restrict__ dwh, const short* __restrict__ dbh,
    short* __restrict__ t, float* __restrict__ gpart)
{
    __shared__ short uh[100 * 128];   // 25600 B
    const int blk = blockIdx.x;
    const int cs  = blk & 1;
    const int txy = blk >> 1;
    const int tx  = txy & 31;
    const int ty  = (txy >> 5) & 31;
    const int b   = txy >> 10;
    const int tid = threadIdx.x;
    const int lane = tid & 63;
    const int wave = tid >> 6;
    const int m    = lane & 15;
    const int quad = lane >> 4;

    // ---- phase 1: two pixel-slots per wave (pA = wave*16+m, pB = pA+64)
    const int pA = wave * 16 + m;
    const int pB = pA + 64;
    const int hyA = (pA * 205) >> 11, hxA = pA - hyA * 10;
    const int hyB = (pB * 205) >> 11, hxB = pB - hyB * 10;
    const int gyA = ty * 8 + hyA - 1, gxA = tx * 8 + hxA - 1;
    const int gyB = ty * 8 + hyB - 1, gxB = tx * 8 + hxB - 1;
    const bool imgA = gyA >= 0 && gyA < 256 && gxA >= 0 && gxA < 256;  // pA<100 always
    const bool imgB = (pB < 100) && gyB >= 0 && gyB < 256 && gxB >= 0 && gxB < 256;
    const bool aliveB = (wave < 3);   // wave3's B slot (p>=112) fully dead

    f32x4 fA[4], fB[4];
#pragma unroll
    for (int i = 0; i < 4; ++i) {
        fA[i] = (f32x4){0.f,0.f,0.f,0.f};
        fB[i] = (f32x4){0.f,0.f,0.f,0.f};
    }
    if (imgA) {
        const float* xr = x + ((long)((b * 256 + gyA) * 256 + gxA)) * 64 + quad * 8;
        fA[0] = *(const f32x4*)(xr);      fA[1] = *(const f32x4*)(xr + 4);
        fA[2] = *(const f32x4*)(xr + 32); fA[3] = *(const f32x4*)(xr + 36);
    }
    if (imgB) {
        const float* xr = x + ((long)((b * 256 + gyB) * 256 + gxB)) * 64 + quad * 8;
        fB[0] = *(const f32x4*)(xr);      fB[1] = *(const f32x4*)(xr + 4);
        fB[2] = *(const f32x4*)(xr + 32); fB[3] = *(const f32x4*)(xr + 36);
    }

    // LN affine params loaded once, shared by both slots
    f32x4 g0 = *(const f32x4*)(ln1g + quad * 8);
    f32x4 g1 = *(const f32x4*)(ln1g + quad * 8 + 4);
    f32x4 g2 = *(const f32x4*)(ln1g + 32 + quad * 8);
    f32x4 g3 = *(const f32x4*)(ln1g + 32 + quad * 8 + 4);
    f32x4 c0 = *(const f32x4*)(ln1b + quad * 8);
    f32x4 c1 = *(const f32x4*)(ln1b + quad * 8 + 4);
    f32x4 c2 = *(const f32x4*)(ln1b + 32 + quad * 8);
    f32x4 c3 = *(const f32x4*)(ln1b + 32 + quad * 8 + 4);

    f16x8 a0A = {0,0,0,0,0,0,0,0}, a1A = {0,0,0,0,0,0,0,0};
    f16x8 a0B = {0,0,0,0,0,0,0,0}, a1B = {0,0,0,0,0,0,0,0};

    if (imgA) {
        float s  = 0.f, s2 = 0.f;
#pragma unroll
        for (int i = 0; i < 4; ++i)
#pragma unroll
            for (int r = 0; r < 4; ++r) { s += fA[i][r]; s2 += fA[i][r] * fA[i][r]; }
        s  += __shfl_xor(s, 16);  s  += __shfl_xor(s, 32);
        s2 += __shfl_xor(s2, 16); s2 += __shfl_xor(s2, 32);
        float mean = s * 0.015625f;
        float var  = s2 * 0.015625f - mean * mean;
        float rs   = rsqrtf(var + 1e-6f);
        float mrs  = mean * rs;
        uint4_t ra, rb;
#define LNP(va,vb,ga,gb,ca,cb) h2u(pkrtz(((va)*rs - mrs)*(ga) + (ca), ((vb)*rs - mrs)*(gb) + (cb)))
        ra[0] = LNP(fA[0][0],fA[0][1],g0[0],g0[1],c0[0],c0[1]);
        ra[1] = LNP(fA[0][2],fA[0][3],g0[2],g0[3],c0[2],c0[3]);
        ra[2] = LNP(fA[1][0],fA[1][1],g1[0],g1[1],c1[0],c1[1]);
        ra[3] = LNP(fA[1][2],fA[1][3],g1[2],g1[3],c1[2],c1[3]);
        rb[0] = LNP(fA[2][0],fA[2][1],g2[0],g2[1],c2[0],c2[1]);
        rb[1] = LNP(fA[2][2],fA[2][3],g2[2],g2[3],c2[2],c2[3]);
        rb[2] = LNP(fA[3][0],fA[3][1],g3[0],g3[1],c3[0],c3[1]);
        rb[3] = LNP(fA[3][2],fA[3][3],g3[2],g3[3],c3[2],c3[3]);
        a0A = __builtin_bit_cast(f16x8, ra);
        a1A = __builtin_bit_cast(f16x8, rb);
    }
    if (imgB) {
        float s  = 0.f, s2 = 0.f;
#pragma unroll
        for (int i = 0; i < 4; ++i)
#pragma unroll
            for (int r = 0; r < 4; ++r) { s += fB[i][r]; s2 += fB[i][r] * fB[i][r]; }
        s  += __shfl_xor(s, 16);  s  += __shfl_xor(s, 32);
        s2 += __shfl_xor(s2, 16); s2 += __shfl_xor(s2, 32);
        float mean = s * 0.015625f;
        float var  = s2 * 0.015625f - mean * mean;
        float rs   = rsqrtf(var + 1e-6f);
        float mrs  = mean * rs;
        uint4_t ra, rb;
        ra[0] = LNP(fB[0][0],fB[0][1],g0[0],g0[1],c0[0],c0[1]);
        ra[1] = LNP(fB[0][2],fB[0][3],g0[2],g0[3],c0[2],c0[3]);
        ra[2] = LNP(fB[1][0],fB[1][1],g1[0],g1[1],c1[0],c1[1]);
        ra[3] = LNP(fB[1][2],fB[1][3],g1[2],g1[3],c1[2],c1[3]);
        rb[0] = LNP(fB[2][0],fB[2][1],g2[0],g2[1],c2[0],c2[1]);
        rb[1] = LNP(fB[2][2],fB[2][3],g2[2],g2[3],c2[2],c2[3]);
        rb[2] = LNP(fB[3][0],fB[3][1],g3[0],g3[1],c3[0],c3[1]);
        rb[3] = LNP(fB[3][2],fB[3][3],g3[2],g3[3],c3[2],c3[3]);
#undef LNP
        a0B = __builtin_bit_cast(f16x8, ra);
        a1B = __builtin_bit_cast(f16x8, rb);
    }

    // MFMA: each w1t/b1 fragment loaded once, feeds both slots
    char* uhc = (char*)uh;
#pragma unroll
    for (int cot = 0; cot < 8; ++cot) {
        const int cob = (cot < 4) ? (cs * 64 + cot * 16) : (128 + cs * 64 + (cot - 4) * 16);
        const f16x8 wlo = __builtin_bit_cast(f16x8, *(const uint4_t*)(w1t + (cob + m) * 64 + quad * 8));
        const f16x8 whi = __builtin_bit_cast(f16x8, *(const uint4_t*)(w1t + (cob + m) * 64 + 32 + quad * 8));
        const f32x4 bv = *(const f32x4*)(b1 + cob + quad * 4);
        {
            f32x4 acc = {0.f,0.f,0.f,0.f};
            acc = __builtin_amdgcn_mfma_f32_16x16x32_f16(wlo, a0A, acc, 0, 0, 0);
            acc = __builtin_amdgcn_mfma_f32_16x16x32_f16(whi, a1A, acc, 0, 0, 0);
            uint2_t pk;
            pk[0] = imgA ? h2u(pkrtz(acc[0] + bv[0], acc[1] + bv[1])) : 0u;
            pk[1] = imgA ? h2u(pkrtz(acc[2] + bv[2], acc[3] + bv[3])) : 0u;
            int off = (pA * 256 + cot * 32 + quad * 8) ^ ((pA & 7) << 4);
            *(uint2_t*)(uhc + off) = pk;
        }
        if (aliveB) {
            f32x4 acc = {0.f,0.f,0.f,0.f};
            acc = __builtin_amdgcn_mfma_f32_16x16x32_f16(wlo, a0B, acc, 0, 0, 0);
            acc = __builtin_amdgcn_mfma_f32_16x16x32_f16(whi, a1B, acc, 0, 0, 0);
            if (pB < 100) {
                uint2_t pk;
                pk[0] = imgB ? h2u(pkrtz(acc[0] + bv[0], acc[1] + bv[1])) : 0u;
                pk[1] = imgB ? h2u(pkrtz(acc[2] + bv[2], acc[3] + bv[3])) : 0u;
                int off = (pB * 256 + cot * 32 + quad * 8) ^ ((pB & 7) << 4);
                *(uint2_t*)(uhc + off) = pk;
            }
        }
    }
    __syncthreads();

    // ---- phase 2: dw3x3 + gate, packed fp16 ----
    const int y = lane >> 3, xx = lane & 7;
    const int cq = wave;
    const int gc0 = cs * 64 + cq * 16;
    const long gpx = ((long)(b * 256 + ty * 8 + y) * 256) + tx * 8 + xx;

    h2 A1[8], A2[8];
#pragma unroll
    for (int j = 0; j < 8; ++j) {
        A1[j] = u2h(0u);
        A2[j] = u2h(0u);
    }
#pragma unroll
    for (int dy = 0; dy < 3; ++dy)
#pragma unroll
    for (int dx = 0; dx < 3; ++dx) {
        int h = (y + dy) * 10 + (xx + dx);
        int sw = (h & 7) << 4;
        int b0 = h * 256 + cq * 32;
        uint4_t u1l  = *(const uint4_t*)(uhc + ((b0)       ^ sw));
        uint4_t u1h  = *(const uint4_t*)(uhc + ((b0 + 16)  ^ sw));
        uint4_t u2l  = *(const uint4_t*)(uhc + ((b0 + 128) ^ sw));
        uint4_t u2hv = *(const uint4_t*)(uhc + ((b0 + 144) ^ sw));
        const uint4_t* wp = (const uint4_t*)(dwh + (dy * 3 + dx) * 256 + gc0);
        const uint4_t* vp = (const uint4_t*)(dwh + (dy * 3 + dx) * 256 + 128 + gc0);
        uint4_t w1l = wp[0], w1h = wp[1];
        uint4_t w2l = vp[0], w2h = vp[1];
#pragma unroll
        for (int j = 0; j < 4; ++j) {
            A1[j]     += u2h(u1l[j])  * u2h(w1l[j]);
            A1[j + 4] += u2h(u1h[j])  * u2h(w1h[j]);
            A2[j]     += u2h(u2l[j])  * u2h(w2l[j]);
            A2[j + 4] += u2h(u2hv[j]) * u2h(w2h[j]);
        }
    }
    const uint4_t* bp1 = (const uint4_t*)(dbh + gc0);
    const uint4_t* bp2 = (const uint4_t*)(dbh + 128 + gc0);
    uint4_t b1l = bp1[0], b1h = bp1[1];
    uint4_t b2l = bp2[0], b2h = bp2[1];
    uint4_t s0, s1;
#pragma unroll
    for (int j = 0; j < 4; ++j) {
        h2 t0 = (A1[j]     + u2h(b1l[j])) * (A2[j]     + u2h(b2l[j]));
        h2 t1 = (A1[j + 4] + u2h(b1h[j])) * (A2[j + 4] + u2h(b2h[j]));
        s0[j] = h2u(t0);
        s1[j] = h2u(t1);
    }
    *(uint4_t*)(t + gpx * 128 + gc0)     = s0;
    *(uint4_t*)(t + gpx * 128 + gc0 + 8) = s1;

    // ---- GAP partials: packed-f16 butterfly over the wave's 64 pixels ----
#pragma unroll
    for (int st = 1; st < 64; st <<= 1) {
#pragma unroll
        for (int j = 0; j < 4; ++j) {
            s0[j] = h2u(u2h(s0[j]) + u2h((unsigned)__shfl_xor((int)s0[j], st)));
            s1[j] = h2u(u2h(s1[j]) + u2h((unsigned)__shfl_xor((int)s1[j], st)));
        }
    }
    if (lane == 0) {
        float* gp = gpart + (long)blk * 64 + cq * 16;
#pragma unroll
        for (int j = 0; j < 4; ++j) {
            h2 v0 = u2h(s0[j]), v1 = u2h(s1[j]);
            f32x2 w0 = {(float)v0[0], (float)v0[1]};
            f32x2 w1 = {(float)v1[0], (float)v1[1]};
            *(f32x2*)(gp + 2 * j)     = w0;
            *(f32x2*)(gp + 8 + 2 * j) = w1;
        }
    }
}

// ---------- K_R2: reduce gpart[16384][64] -> gpart2[64][128] (4 MB read) ----------
__global__ __launch_bounds__(256) void k_red2(
    const float* __restrict__ gpart, float* __restrict__ gpart2)
{
    __shared__ float red[2][128];
    const int b = blockIdx.x >> 3;      // batch
    const int sg = blockIdx.x & 7;      // txy segment (128 tiles each)
    const int tid = threadIdx.x;
    const int c = tid & 127, h = tid >> 7;
    const int cs = c >> 6, lc = c & 63;
    float acc = 0.f;
#pragma unroll 4
    for (int i = 0; i < 64; ++i) {
        int txy = sg * 128 + h * 64 + i;
        acc += gpart[((long)(b * 1024 + txy) * 2 + cs) * 64 + lc];
    }
    red[h][c] = acc;
    __syncthreads();
    if (tid < 128) gpart2[(b * 8 + sg) * 128 + c] = red[0][c] + red[1][c];
}

// ---------- K_S: final GAP + SCA matmul (8 blocks, one per batch) ----------
__global__ __launch_bounds__(256) void k_sca3(
    const float* __restrict__ gpart2, const float* __restrict__ scaw,
    const float* __restrict__ scab, float* __restrict__ watt)
{
    __shared__ float gn[128];
    const int b = blockIdx.x;
    const int tid = threadIdx.x;
    if (tid < 128) {
        float s = 0.f;
#pragma unroll
        for (int sg = 0; sg < 8; ++sg) s += gpart2[(b * 8 + sg) * 128 + tid];
        gn[tid] = s * (1.0f / 65536.0f);
    }
    __syncthreads();
    if (tid < 128) {
        float acc = scab[tid];
        for (int ci = 0; ci < 128; ++ci) acc += gn[ci] * scaw[ci * 128 + tid];
        watt[b * 128 + tid] = acc;
    }
}

// ---------- K_B: pw2 + residual + LN2 + pw3 + gate + pw4 + residual ----------
// TWO pixel-groups per wave (A at px, B at px+64): every weight fragment is
// loaded once and feeds two MFMAs (halves L1/L2 weight traffic, doubles
// per-wave ILP). Registers deliberately spend the free headroom of the
// 65..128 VGPR occupancy step. xl/zt are per-(wave,group)-private slabs:
// no __syncthreads anywhere (lgkmcnt orders write->read within a wave).
#define XLST 72
#define ZTST 136
__global__ __launch_bounds__(256) void k_b(
    const short* __restrict__ t, const float* __restrict__ watt,
    const short* __restrict__ w2t, const float* __restrict__ b2,
    const float* __restrict__ x, const float* __restrict__ beta,
    const float* __restrict__ ln2g, const float* __restrict__ ln2b,
    const short* __restrict__ w3t, const float* __restrict__ b3,
    const short* __restrict__ w4t, const float* __restrict__ b4,
    const float* __restrict__ gamma, float* __restrict__ out)
{
    __shared__ short xl[8][16 * XLST];   // 18432 B
    __shared__ short zt[8][16 * ZTST];   // 34816 B
    const int lane = threadIdx.x & 63;
    const int wave = threadIdx.x >> 6;
    const int m = lane & 15, quad = lane >> 4;
    const long pxA = (long)blockIdx.x * 128 + wave * 16 + m;
    const long pxB = pxA + 64;
    const int b = (int)(((long)blockIdx.x * 128) >> 16);
    const float* wa = watt + b * 128;
    const int sA = wave, sB = wave + 4;

    // residual x loads first (both groups): latency hides under t-load + pw2
    f32x4 xvA[4], xvB[4];
#pragma unroll
    for (int nt = 0; nt < 4; ++nt) {
        xvA[nt] = *(const f32x4*)(x + pxA * 64 + nt * 16 + quad * 4);
        xvB[nt] = *(const f32x4*)(x + pxB * 64 + nt * 16 + quad * 4);
    }

    const short* trA = t + pxA * 128;
    const short* trB = t + pxB * 128;
    f32x4 acc2A[4], acc2B[4];
#pragma unroll
    for (int nt = 0; nt < 4; ++nt) {
        acc2A[nt] = (f32x4){0.f,0.f,0.f,0.f};
        acc2B[nt] = (f32x4){0.f,0.f,0.f,0.f};
    }
#pragma unroll
    for (int kh = 0; kh < 4; ++kh) {
        uint4_t tA = *(const uint4_t*)(trA + kh * 32 + quad * 8);
        uint4_t tB = *(const uint4_t*)(trB + kh * 32 + quad * 8);
        f32x4 w0  = *(const f32x4*)(wa + kh * 32 + quad * 8);
        f32x4 w1v = *(const f32x4*)(wa + kh * 32 + quad * 8 + 4);
        h2 s01 = pkrtz(w0[0], w0[1]),  s23 = pkrtz(w0[2], w0[3]);
        h2 s45 = pkrtz(w1v[0], w1v[1]), s67 = pkrtz(w1v[2], w1v[3]);
        uint4_t oA, oB;
        oA[0] = h2u(u2h(tA[0]) * s01); oA[1] = h2u(u2h(tA[1]) * s23);
        oA[2] = h2u(u2h(tA[2]) * s45); oA[3] = h2u(u2h(tA[3]) * s67);
        oB[0] = h2u(u2h(tB[0]) * s01); oB[1] = h2u(u2h(tB[1]) * s23);
        oB[2] = h2u(u2h(tB[2]) * s45); oB[3] = h2u(u2h(tB[3]) * s67);
        f16x8 bfrA = __builtin_bit_cast(f16x8, oA);
        f16x8 bfrB = __builtin_bit_cast(f16x8, oB);
#pragma unroll
        for (int nt = 0; nt < 4; ++nt) {
            f16x8 aw = __builtin_bit_cast(f16x8,
                *(const uint4_t*)(w2t + (nt * 16 + m) * 128 + kh * 32 + quad * 8));
            acc2A[nt] = __builtin_amdgcn_mfma_f32_16x16x32_f16(aw, bfrA, acc2A[nt], 0, 0, 0);
            acc2B[nt] = __builtin_amdgcn_mfma_f32_16x16x32_f16(aw, bfrB, acc2B[nt], 0, 0, 0);
        }
    }
    float x1A[4][4], x1B[4][4];
#pragma unroll
    for (int nt = 0; nt < 4; ++nt) {
        int cob = nt * 16 + quad * 4;
        f32x4 bb = *(const f32x4*)(b2 + cob);
        f32x4 be = *(const f32x4*)(beta + cob);
#pragma unroll
        for (int r = 0; r < 4; ++r) {
            x1A[nt][r] = xvA[nt][r] + (acc2A[nt][r] + bb[r]) * be[r];
            x1B[nt][r] = xvB[nt][r] + (acc2B[nt][r] + bb[r]) * be[r];
        }
    }
    // LN2 for both groups
    float sa = 0.f, s2a = 0.f, sb = 0.f, s2b = 0.f;
#pragma unroll
    for (int nt = 0; nt < 4; ++nt)
#pragma unroll
        for (int r = 0; r < 4; ++r) {
            sa += x1A[nt][r]; s2a += x1A[nt][r] * x1A[nt][r];
            sb += x1B[nt][r]; s2b += x1B[nt][r] * x1B[nt][r];
        }
    sa  += __shfl_xor(sa, 16);  sa  += __shfl_xor(sa, 32);
    s2a += __shfl_xor(s2a, 16); s2a += __shfl_xor(s2a, 32);
    sb  += __shfl_xor(sb, 16);  sb  += __shfl_xor(sb, 32);
    s2b += __shfl_xor(s2b, 16); s2b += __shfl_xor(s2b, 32);
    float meanA = sa * 0.015625f;
    float varA  = s2a * 0.015625f - meanA * meanA;
    float rsA   = rsqrtf(varA + 1e-6f);
    float mrsA  = meanA * rsA;
    float meanB = sb * 0.015625f;
    float varB  = s2b * 0.015625f - meanB * meanB;
    float rsB   = rsqrtf(varB + 1e-6f);
    float mrsB  = meanB * rsB;
#pragma unroll
    for (int nt = 0; nt < 4; ++nt) {
        int cob = nt * 16 + quad * 4;
        f32x4 gg = *(const f32x4*)(ln2g + cob);
        f32x4 cc = *(const f32x4*)(ln2b + cob);
        uint2_t pkA, pkB;
        pkA[0] = h2u(pkrtz((x1A[nt][0] * rsA - mrsA) * gg[0] + cc[0],
                           (x1A[nt][1] * rsA - mrsA) * gg[1] + cc[1]));
        pkA[1] = h2u(pkrtz((x1A[nt][2] * rsA - mrsA) * gg[2] + cc[2],
                           (x1A[nt][3] * rsA - mrsA) * gg[3] + cc[3]));
        pkB[0] = h2u(pkrtz((x1B[nt][0] * rsB - mrsB) * gg[0] + cc[0],
                           (x1B[nt][1] * rsB - mrsB) * gg[1] + cc[1]));
        pkB[1] = h2u(pkrtz((x1B[nt][2] * rsB - mrsB) * gg[2] + cc[2],
                           (x1B[nt][3] * rsB - mrsB) * gg[3] + cc[3]));
        *(uint2_t*)&xl[sA][m * XLST + cob] = pkA;
        *(uint2_t*)&xl[sB][m * XLST + cob] = pkB;
    }
    // no barrier: xl slabs are wave-private
    f16x8 xbA0 = __builtin_bit_cast(f16x8, *(const uint4_t*)&xl[sA][m * XLST + quad * 8]);
    f16x8 xbA1 = __builtin_bit_cast(f16x8, *(const uint4_t*)&xl[sA][m * XLST + 32 + quad * 8]);
    f16x8 xbB0 = __builtin_bit_cast(f16x8, *(const uint4_t*)&xl[sB][m * XLST + quad * 8]);
    f16x8 xbB1 = __builtin_bit_cast(f16x8, *(const uint4_t*)&xl[sB][m * XLST + 32 + quad * 8]);
#pragma unroll
    for (int pg = 0; pg < 8; ++pg) {
        f16x8 w3a0 = __builtin_bit_cast(f16x8, *(const uint4_t*)(w3t + (pg * 16 + m) * 64 + quad * 8));
        f16x8 w3a1 = __builtin_bit_cast(f16x8, *(const uint4_t*)(w3t + (pg * 16 + m) * 64 + 32 + quad * 8));
        f16x8 w3b0 = __builtin_bit_cast(f16x8, *(const uint4_t*)(w3t + (128 + pg * 16 + m) * 64 + quad * 8));
        f16x8 w3b1 = __builtin_bit_cast(f16x8, *(const uint4_t*)(w3t + (128 + pg * 16 + m) * 64 + 32 + quad * 8));
        f32x4 aAA = {0.f,0.f,0.f,0.f}, aBA = {0.f,0.f,0.f,0.f};
        f32x4 aAB = {0.f,0.f,0.f,0.f}, aBB = {0.f,0.f,0.f,0.f};
        aAA = __builtin_amdgcn_mfma_f32_16x16x32_f16(w3a0, xbA0, aAA, 0, 0, 0);
        aAA = __builtin_amdgcn_mfma_f32_16x16x32_f16(w3a1, xbA1, aAA, 0, 0, 0);
        aBA = __builtin_amdgcn_mfma_f32_16x16x32_f16(w3b0, xbA0, aBA, 0, 0, 0);
        aBA = __builtin_amdgcn_mfma_f32_16x16x32_f16(w3b1, xbA1, aBA, 0, 0, 0);
        aAB = __builtin_amdgcn_mfma_f32_16x16x32_f16(w3a0, xbB0, aAB, 0, 0, 0);
        aAB = __builtin_amdgcn_mfma_f32_16x16x32_f16(w3a1, xbB1, aAB, 0, 0, 0);
        aBB = __builtin_amdgcn_mfma_f32_16x16x32_f16(w3b0, xbB0, aBB, 0, 0, 0);
        aBB = __builtin_amdgcn_mfma_f32_16x16x32_f16(w3b1, xbB1, aBB, 0, 0, 0);
        int cb = pg * 16 + quad * 4;
        f32x4 bA_ = *(const f32x4*)(b3 + cb);
        f32x4 bB_ = *(const f32x4*)(b3 + 128 + cb);
        uint2_t pkA, pkB;
        pkA[0] = h2u(pkrtz((aAA[0] + bA_[0]) * (aBA[0] + bB_[0]),
                           (aAA[1] + bA_[1]) * (aBA[1] + bB_[1])));
        pkA[1] = h2u(pkrtz((aAA[2] + bA_[2]) * (aBA[2] + bB_[2]),
                           (aAA[3] + bA_[3]) * (aBA[3] + bB_[3])));
        pkB[0] = h2u(pkrtz((aAB[0] + bA_[0]) * (aBB[0] + bB_[0]),
                           (aAB[1] + bA_[1]) * (aBB[1] + bB_[1])));
        pkB[1] = h2u(pkrtz((aAB[2] + bA_[2]) * (aBB[2] + bB_[2]),
                           (aAB[3] + bA_[3]) * (aBB[3] + bB_[3])));
        *(uint2_t*)&zt[sA][m * ZTST + cb] = pkA;
        *(uint2_t*)&zt[sB][m * ZTST + cb] = pkB;
    }
    // no barrier: zt slabs are wave-private
    f32x4 acc4A[4], acc4B[4];
#pragma unroll
    for (int nt = 0; nt < 4; ++nt) {
        acc4A[nt] = (f32x4){0.f,0.f,0.f,0.f};
        acc4B[nt] = (f32x4){0.f,0.f,0.f,0.f};
    }
#pragma unroll
    for (int kh = 0; kh < 4; ++kh) {
        f16x8 zbA = __builtin_bit_cast(f16x8, *(const uint4_t*)&zt[sA][m * ZTST + kh * 32 + quad * 8]);
        f16x8 zbB = __builtin_bit_cast(f16x8, *(const uint4_t*)&zt[sB][m * ZTST + kh * 32 + quad * 8]);
#pragma unroll
        for (int nt = 0; nt < 4; ++nt) {
            f16x8 aw = __builtin_bit_cast(f16x8,
                *(const uint4_t*)(w4t + (nt * 16 + m) * 128 + kh * 32 + quad * 8));
            acc4A[nt] = __builtin_amdgcn_mfma_f32_16x16x32_f16(aw, zbA, acc4A[nt], 0, 0, 0);
            acc4B[nt] = __builtin_amdgcn_mfma_f32_16x16x32_f16(aw, zbB, acc4B[nt], 0, 0, 0);
        }
    }
#pragma unroll
    for (int nt = 0; nt < 4; ++nt) {
        int cob = nt * 16 + quad * 4;
        f32x4 bb = *(const f32x4*)(b4 + cob);
        f32x4 gm = *(const f32x4*)(gamma + cob);
        f32x4 oA, oB;
#pragma unroll
        for (int r = 0; r < 4; ++r) {
            oA[r] = x1A[nt][r] + (acc4A[nt][r] + bb[r]) * gm[r];
            oB[r] = x1B[nt][r] + (acc4B[nt][r] + bb[r]) * gm[r];
        }
        *(f32x4*)(out + pxA * 64 + cob) = oA;
        *(f32x4*)(out + pxB * 64 + cob) = oB;
    }
}

// ---------- launch ----------
extern "C" void kernel_launch(void* const* d_in, const int* in_sizes, int n_in,
                              void* d_out, int out_size, void* d_ws, size_t ws_size,
                              hipStream_t stream) {
    (void)in_sizes; (void)n_in; (void)out_size; (void)ws_size;
    const float* x    = (const float*)d_in[0];
    const float* ln1g = (const float*)d_in[1];
    const float* ln1b = (const float*)d_in[2];
    const float* pw1w = (const float*)d_in[3];
    const float* pw1b = (const float*)d_in[4];
    const float* dww  = (const float*)d_in[5];
    const float* dwb  = (const float*)d_in[6];
    const float* scaw = (const float*)d_in[7];
    const float* scab = (const float*)d_in[8];
    const float* pw2w = (const float*)d_in[9];
    const float* pw2b = (const float*)d_in[10];
    const float* beta = (const float*)d_in[11];
    const float* ln2g = (const float*)d_in[12];
    const float* ln2b = (const float*)d_in[13];
    const float* pw3w = (const float*)d_in[14];
    const float* pw3b = (const float*)d_in[15];
    const float* pw4w = (const float*)d_in[16];
    const float* pw4b = (const float*)d_in[17];
    const float* gamma= (const float*)d_in[18];

    char* ws = (char*)d_ws;
    short* w1t = (short*)(ws + OFF_W1T);
    short* w2t = (short*)(ws + OFF_W2T);
    short* w3t = (short*)(ws + OFF_W3T);
    short* w4t = (short*)(ws + OFF_W4T);
    short* dwh = (short*)(ws + OFF_DWH);
    short* dbh = (short*)(ws + OFF_DBH);
    float* watt = (float*)(ws + OFF_WATT);
    float* gpart = (float*)(ws + OFF_GPART);
    float* gpart2 = (float*)(ws + OFF_GPART2);
    short* t   = (short*)(ws + OFF_T);
    float* out = (float*)d_out;

    k_prep<<<64, 256, 0, stream>>>(pw1w, pw2w, pw3w, pw4w, dww, dwb,
                                   w1t, w2t, w3t, w4t, dwh, dbh);
    k_a<<<16384, 256, 0, stream>>>(x, ln1g, ln1b, w1t, pw1b, dwh, dbh, t, gpart);
    k_red2<<<64, 256, 0, stream>>>(gpart, gpart2);
    k_sca3<<<8, 256, 0, stream>>>(gpart2, scaw, scab, watt);
    k_b<<<4096, 256, 0, stream>>>(t, watt, w2t, pw2b, x, beta, ln2g, ln2b,
                                  w3t, pw3b, w4t, pw4b, gamma, out);
}

// Round 11
// 692.250 us; speedup vs baseline: 1.4775x; 1.0074x over previous
//
#include <hip/hip_runtime.h>

// ---------- types / helpers ----------
typedef __attribute__((ext_vector_type(8))) _Float16 f16x8;
typedef __attribute__((ext_vector_type(2))) _Float16 h2;
typedef __attribute__((ext_vector_type(4))) float f32x4;
typedef __attribute__((ext_vector_type(2))) float f32x2;
typedef __attribute__((ext_vector_type(4))) unsigned uint4_t;
typedef __attribute__((ext_vector_type(2))) unsigned uint2_t;

__device__ __forceinline__ h2 pkrtz(float a, float b) {
    return __builtin_bit_cast(h2, __builtin_amdgcn_cvt_pkrtz(a, b));   // v_cvt_pkrtz_f16_f32
}
__device__ __forceinline__ unsigned h2u(h2 v) { return __builtin_bit_cast(unsigned, v); }
__device__ __forceinline__ h2 u2h(unsigned u) { return __builtin_bit_cast(h2, u); }
__device__ __forceinline__ short f2h(float f) { return __builtin_bit_cast(short, (_Float16)f); }

// ws layout (bytes)
#define OFF_W1T 0L            // 32768
#define OFF_W2T 32768L        // 16384
#define OFF_W3T 49152L        // 32768
#define OFF_W4T 81920L        // 16384
#define OFF_DWH 98304L        // 4608
#define OFF_DBH 102912L       // 512
#define OFF_WATT 103424L      // 4096
#define OFF_GPART 107520L     // 16384*64*4 = 4194304
#define OFF_GPART2 4301824L   // 64*128*4 = 32768
#define OFF_T 4334592L        // 524288*128*2 = 134217728

// ---------- K0: weight transpose + fp16 cast ----------
__global__ __launch_bounds__(256) void k_prep(
    const float* __restrict__ w1, const float* __restrict__ w2,
    const float* __restrict__ w3, const float* __restrict__ w4,
    const float* __restrict__ dww, const float* __restrict__ dwb,
    short* __restrict__ w1t, short* __restrict__ w2t,
    short* __restrict__ w3t, short* __restrict__ w4t,
    short* __restrict__ dwh, short* __restrict__ dbh)
{
    int id = blockIdx.x * 256 + threadIdx.x;
    if (id < 64 * 256) {
        int ci = id >> 8, co = id & 255;
        w1t[co * 64 + ci] = f2h(w1[id]);
        w3t[co * 64 + ci] = f2h(w3[id]);
    }
    if (id < 128 * 64) {
        int ci = id >> 6, co = id & 63;
        w2t[co * 128 + ci] = f2h(w2[id]);
        w4t[co * 128 + ci] = f2h(w4[id]);
    }
    if (id < 9 * 256) dwh[id] = f2h(dww[id]);
    if (id < 256)     dbh[id] = f2h(dwb[id]);
}

// ---------- K_A: LN1 + pw1(MFMA) + dw3x3 + gate + GAP partials ----------
// LDS: u tile [100 rows][128 shorts], XOR-swizzled (byte ^= (row&7)<<4).
// 25600 B -> 6 blocks/CU.  XCD-pairing blockIdx swizzle: the cs=0/1 blocks
// of one spatial tile land on ADJACENT slots of the SAME XCD so the shared
// x-halo is an L2 hit for the second block (round-robin i%8 mapping).
__global__ __launch_bounds__(256) void k_a(
    const float* __restrict__ x, const float* __restrict__ ln1g, const float* __restrict__ ln1b,
    const short* __restrict__ w1t, const float* __restrict__ b1,
    const short* __restrict__ dwh, const short* __restrict__ dbh,
    short* __restrict__ t, float* __restrict__ gpart)
{
    __shared__ short uh[100 * 128];   // 25600 B
    const int i    = blockIdx.x;
    const int xcd  = i & 7;
    const int slot = i >> 3;
    const int cs   = slot & 1;
    const int p    = xcd * 1024 + (slot >> 1);   // logical tile 0..8191
    const int lblk = p * 2 + cs;                 // logical block for gpart layout
    const int tx  = p & 31;
    const int ty  = (p >> 5) & 31;
    const int b   = p >> 10;
    const int tid = threadIdx.x;
    const int lane = tid & 63;
    const int wave = tid >> 6;
    const int m    = lane & 15;
    const int quad = lane >> 4;

    // ---- phase 1: two pixel-slots per wave (pA = wave*16+m, pB = pA+64)
    const int pA = wave * 16 + m;
    const int pB = pA + 64;
    const int hyA = (pA * 205) >> 11, hxA = pA - hyA * 10;
    const int hyB = (pB * 205) >> 11, hxB = pB - hyB * 10;
    const int gyA = ty * 8 + hyA - 1, gxA = tx * 8 + hxA - 1;
    const int gyB = ty * 8 + hyB - 1, gxB = tx * 8 + hxB - 1;
    const bool imgA = gyA >= 0 && gyA < 256 && gxA >= 0 && gxA < 256;  // pA<100 always
    const bool imgB = (pB < 100) && gyB >= 0 && gyB < 256 && gxB >= 0 && gxB < 256;
    const bool aliveB = (wave < 3);   // wave3's B slot (p>=112) fully dead

    f32x4 fA[4], fB[4];
#pragma unroll
    for (int j = 0; j < 4; ++j) {
        fA[j] = (f32x4){0.f,0.f,0.f,0.f};
        fB[j] = (f32x4){0.f,0.f,0.f,0.f};
    }
    if (imgA) {
        const float* xr = x + ((long)((b * 256 + gyA) * 256 + gxA)) * 64 + quad * 8;
        fA[0] = *(const f32x4*)(xr);      fA[1] = *(const f32x4*)(xr + 4);
        fA[2] = *(const f32x4*)(xr + 32); fA[3] = *(const f32x4*)(xr + 36);
    }
    if (imgB) {
        const float* xr = x + ((long)((b * 256 + gyB) * 256 + gxB)) * 64 + quad * 8;
        fB[0] = *(const f32x4*)(xr);      fB[1] = *(const f32x4*)(xr + 4);
        fB[2] = *(const f32x4*)(xr + 32); fB[3] = *(const f32x4*)(xr + 36);
    }

    // LN affine params loaded once, shared by both slots
    f32x4 g0 = *(const f32x4*)(ln1g + quad * 8);
    f32x4 g1 = *(const f32x4*)(ln1g + quad * 8 + 4);
    f32x4 g2 = *(const f32x4*)(ln1g + 32 + quad * 8);
    f32x4 g3 = *(const f32x4*)(ln1g + 32 + quad * 8 + 4);
    f32x4 c0 = *(const f32x4*)(ln1b + quad * 8);
    f32x4 c1 = *(const f32x4*)(ln1b + quad * 8 + 4);
    f32x4 c2 = *(const f32x4*)(ln1b + 32 + quad * 8);
    f32x4 c3 = *(const f32x4*)(ln1b + 32 + quad * 8 + 4);

    f16x8 a0A = {0,0,0,0,0,0,0,0}, a1A = {0,0,0,0,0,0,0,0};
    f16x8 a0B = {0,0,0,0,0,0,0,0}, a1B = {0,0,0,0,0,0,0,0};

    if (imgA) {
        float s  = 0.f, s2 = 0.f;
#pragma unroll
        for (int j = 0; j < 4; ++j)
#pragma unroll
            for (int r = 0; r < 4; ++r) { s += fA[j][r]; s2 += fA[j][r] * fA[j][r]; }
        s  += __shfl_xor(s, 16);  s  += __shfl_xor(s, 32);
        s2 += __shfl_xor(s2, 16); s2 += __shfl_xor(s2, 32);
        float mean = s * 0.015625f;
        float var  = s2 * 0.015625f - mean * mean;
        float rs   = rsqrtf(var + 1e-6f);
        float mrs  = mean * rs;
        uint4_t ra, rb;
#define LNP(va,vb,ga,gb,ca,cb) h2u(pkrtz(((va)*rs - mrs)*(ga) + (ca), ((vb)*rs - mrs)*(gb) + (cb)))
        ra[0] = LNP(fA[0][0],fA[0][1],g0[0],g0[1],c0[0],c0[1]);
        ra[1] = LNP(fA[0][2],fA[0][3],g0[2],g0[3],c0[2],c0[3]);
        ra[2] = LNP(fA[1][0],fA[1][1],g1[0],g1[1],c1[0],c1[1]);
        ra[3] = LNP(fA[1][2],fA[1][3],g1[2],g1[3],c1[2],c1[3]);
        rb[0] = LNP(fA[2][0],fA[2][1],g2[0],g2[1],c2[0],c2[1]);
        rb[1] = LNP(fA[2][2],fA[2][3],g2[2],g2[3],c2[2],c2[3]);
        rb[2] = LNP(fA[3][0],fA[3][1],g3[0],g3[1],c3[0],c3[1]);
        rb[3] = LNP(fA[3][2],fA[3][3],g3[2],g3[3],c3[2],c3[3]);
        a0A = __builtin_bit_cast(f16x8, ra);
        a1A = __builtin_bit_cast(f16x8, rb);
    }
    if (imgB) {
        float s  = 0.f, s2 = 0.f;
#pragma unroll
        for (int j = 0; j < 4; ++j)
#pragma unroll
            for (int r = 0; r < 4; ++r) { s += fB[j][r]; s2 += fB[j][r] * fB[j][r]; }
        s  += __shfl_xor(s, 16);  s  += __shfl_xor(s, 32);
        s2 += __shfl_xor(s2, 16); s2 += __shfl_xor(s2, 32);
        float mean = s * 0.015625f;
        float var  = s2 * 0.015625f - mean * mean;
        float rs   = rsqrtf(var + 1e-6f);
        float mrs  = mean * rs;
        uint4_t ra, rb;
        ra[0] = LNP(fB[0][0],fB[0][1],g0[0],g0[1],c0[0],c0[1]);
        ra[1] = LNP(fB[0][2],fB[0][3],g0[2],g0[3],c0[2],c0[3]);
        ra[2] = LNP(fB[1][0],fB[1][1],g1[0],g1[1],c1[0],c1[1]);
        ra[3] = LNP(fB[1][2],fB[1][3],g1[2],g1[3],c1[2],c1[3]);
        rb[0] = LNP(fB[2][0],fB[2][1],g2[0],g2[1],c2[0],c2[1]);
        rb[1] = LNP(fB[2][2],fB[2][3],g2[2],g2[3],c2[2],c2[3]);
        rb[2] = LNP(fB[3][0],fB[3][1],g3[0],g3[1],c3[0],c3[1]);
        rb[3] = LNP(fB[3][2],fB[3][3],g3[2],g3[3],c3[2],c3[3]);
#undef LNP
        a0B = __builtin_bit_cast(f16x8, ra);
        a1B = __builtin_bit_cast(f16x8, rb);
    }

    // MFMA: each w1t/b1 fragment loaded once, feeds both slots
    char* uhc = (char*)uh;
#pragma unroll
    for (int cot = 0; cot < 8; ++cot) {
        const int cob = (cot < 4) ? (cs * 64 + cot * 16) : (128 + cs * 64 + (cot - 4) * 16);
        const f16x8 wlo = __builtin_bit_cast(f16x8, *(const uint4_t*)(w1t + (cob + m) * 64 + quad * 8));
        const f16x8 whi = __builtin_bit_cast(f16x8, *(const uint4_t*)(w1t + (cob + m) * 64 + 32 + quad * 8));
        const f32x4 bv = *(const f32x4*)(b1 + cob + quad * 4);
        {
            f32x4 acc = {0.f,0.f,0.f,0.f};
            acc = __builtin_amdgcn_mfma_f32_16x16x32_f16(wlo, a0A, acc, 0, 0, 0);
            acc = __builtin_amdgcn_mfma_f32_16x16x32_f16(whi, a1A, acc, 0, 0, 0);
            uint2_t pk;
            pk[0] = imgA ? h2u(pkrtz(acc[0] + bv[0], acc[1] + bv[1])) : 0u;
            pk[1] = imgA ? h2u(pkrtz(acc[2] + bv[2], acc[3] + bv[3])) : 0u;
            int off = (pA * 256 + cot * 32 + quad * 8) ^ ((pA & 7) << 4);
            *(uint2_t*)(uhc + off) = pk;
        }
        if (aliveB) {
            f32x4 acc = {0.f,0.f,0.f,0.f};
            acc = __builtin_amdgcn_mfma_f32_16x16x32_f16(wlo, a0B, acc, 0, 0, 0);
            acc = __builtin_amdgcn_mfma_f32_16x16x32_f16(whi, a1B, acc, 0, 0, 0);
            if (pB < 100) {
                uint2_t pk;
                pk[0] = imgB ? h2u(pkrtz(acc[0] + bv[0], acc[1] + bv[1])) : 0u;
                pk[1] = imgB ? h2u(pkrtz(acc[2] + bv[2], acc[3] + bv[3])) : 0u;
                int off = (pB * 256 + cot * 32 + quad * 8) ^ ((pB & 7) << 4);
                *(uint2_t*)(uhc + off) = pk;
            }
        }
    }
    __syncthreads();

    // ---- phase 2: dw3x3 + gate, packed fp16 ----
    const int y = lane >> 3, xx = lane & 7;
    const int cq = wave;
    const int gc0 = cs * 64 + cq * 16;
    const long gpx = ((long)(b * 256 + ty * 8 + y) * 256) + tx * 8 + xx;

    h2 A1[8], A2[8];
#pragma unroll
    for (int j = 0; j < 8; ++j) {
        A1[j] = u2h(0u);
        A2[j] = u2h(0u);
    }
#pragma unroll
    for (int dy = 0; dy < 3; ++dy)
#pragma unroll
    for (int dx = 0; dx < 3; ++dx) {
        int h = (y + dy) * 10 + (xx + dx);
        int sw = (h & 7) << 4;
        int b0 = h * 256 + cq * 32;
        uint4_t u1l  = *(const uint4_t*)(uhc + ((b0)       ^ sw));
        uint4_t u1h  = *(const uint4_t*)(uhc + ((b0 + 16)  ^ sw));
        uint4_t u2l  = *(const uint4_t*)(uhc + ((b0 + 128) ^ sw));
        uint4_t u2hv = *(const uint4_t*)(uhc + ((b0 + 144) ^ sw));
        const uint4_t* wp = (const uint4_t*)(dwh + (dy * 3 + dx) * 256 + gc0);
        const uint4_t* vp = (const uint4_t*)(dwh + (dy * 3 + dx) * 256 + 128 + gc0);
        uint4_t w1l = wp[0], w1h = wp[1];
        uint4_t w2l = vp[0], w2h = vp[1];
#pragma unroll
        for (int j = 0; j < 4; ++j) {
            A1[j]     += u2h(u1l[j])  * u2h(w1l[j]);
            A1[j + 4] += u2h(u1h[j])  * u2h(w1h[j]);
            A2[j]     += u2h(u2l[j])  * u2h(w2l[j]);
            A2[j + 4] += u2h(u2hv[j]) * u2h(w2h[j]);
        }
    }
    const uint4_t* bp1 = (const uint4_t*)(dbh + gc0);
    const uint4_t* bp2 = (const uint4_t*)(dbh + 128 + gc0);
    uint4_t b1l = bp1[0], b1h = bp1[1];
    uint4_t b2l = bp2[0], b2h = bp2[1];
    uint4_t s0, s1;
#pragma unroll
    for (int j = 0; j < 4; ++j) {
        h2 t0 = (A1[j]     + u2h(b1l[j])) * (A2[j]     + u2h(b2l[j]));
        h2 t1 = (A1[j + 4] + u2h(b1h[j])) * (A2[j + 4] + u2h(b2h[j]));
        s0[j] = h2u(t0);
        s1[j] = h2u(t1);
    }
    *(uint4_t*)(t + gpx * 128 + gc0)     = s0;
    *(uint4_t*)(t + gpx * 128 + gc0 + 8) = s1;

    // ---- GAP partials: packed-f16 butterfly over the wave's 64 pixels ----
#pragma unroll
    for (int st = 1; st < 64; st <<= 1) {
#pragma unroll
        for (int j = 0; j < 4; ++j) {
            s0[j] = h2u(u2h(s0[j]) + u2h((unsigned)__shfl_xor((int)s0[j], st)));
            s1[j] = h2u(u2h(s1[j]) + u2h((unsigned)__shfl_xor((int)s1[j], st)));
        }
    }
    if (lane == 0) {
        float* gp = gpart + (long)lblk * 64 + cq * 16;
#pragma unroll
        for (int j = 0; j < 4; ++j) {
            h2 v0 = u2h(s0[j]), v1 = u2h(s1[j]);
            f32x2 w0 = {(float)v0[0], (float)v0[1]};
            f32x2 w1 = {(float)v1[0], (float)v1[1]};
            *(f32x2*)(gp + 2 * j)     = w0;
            *(f32x2*)(gp + 8 + 2 * j) = w1;
        }
    }
}

// ---------- K_R2: reduce gpart[16384][64] -> gpart2[64][128] (4 MB read) ----------
__global__ __launch_bounds__(256) void k_red2(
    const float* __restrict__ gpart, float* __restrict__ gpart2)
{
    __shared__ float red[2][128];
    const int b = blockIdx.x >> 3;      // batch
    const int sg = blockIdx.x & 7;      // txy segment (128 tiles each)
    const int tid = threadIdx.x;
    const int c = tid & 127, h = tid >> 7;
    const int cs = c >> 6, lc = c & 63;
    float acc = 0.f;
#pragma unroll 4
    for (int i = 0; i < 64; ++i) {
        int txy = sg * 128 + h * 64 + i;
        acc += gpart[((long)(b * 1024 + txy) * 2 + cs) * 64 + lc];
    }
    red[h][c] = acc;
    __syncthreads();
    if (tid < 128) gpart2[(b * 8 + sg) * 128 + c] = red[0][c] + red[1][c];
}

// ---------- K_S: final GAP + SCA matmul (8 blocks, one per batch) ----------
__global__ __launch_bounds__(256) void k_sca3(
    const float* __restrict__ gpart2, const float* __restrict__ scaw,
    const float* __restrict__ scab, float* __restrict__ watt)
{
    __shared__ float gn[128];
    const int b = blockIdx.x;
    const int tid = threadIdx.x;
    if (tid < 128) {
        float s = 0.f;
#pragma unroll
        for (int sg = 0; sg < 8; ++sg) s += gpart2[(b * 8 + sg) * 128 + tid];
        gn[tid] = s * (1.0f / 65536.0f);
    }
    __syncthreads();
    if (tid < 128) {
        float acc = scab[tid];
        for (int ci = 0; ci < 128; ++ci) acc += gn[ci] * scaw[ci * 128 + tid];
        watt[b * 128 + tid] = acc;
    }
}

// ---------- K_B: pw2 + residual + LN2 + pw3 + gate + pw4 + residual ----------
// TWO pixel-groups per wave (A at px, B at px+64): every weight fragment is
// loaded once and feeds two MFMAs. xl and zt SHARE one LDS buffer (xz):
// all xl data is consumed into registers (xbA0..xbB1) before the first zt
// write; slabs are wave-private and DS is in-order per wave, and the
// compiler must preserve order on may-aliasing same-array accesses.
// LDS 53248 -> 34816 B => 3 -> 4 blocks/CU.
#define ZTST 136
__global__ __launch_bounds__(256) void k_b(
    const short* __restrict__ t, const float* __restrict__ watt,
    const short* __restrict__ w2t, const float* __restrict__ b2,
    const float* __restrict__ x, const float* __restrict__ beta,
    const float* __restrict__ ln2g, const float* __restrict__ ln2b,
    const short* __restrict__ w3t, const float* __restrict__ b3,
    const short* __restrict__ w4t, const float* __restrict__ b4,
    const float* __restrict__ gamma, float* __restrict__ out)
{
    __shared__ short xz[8][16 * ZTST];   // 34816 B (xl phase, then zt phase)
    const int lane = threadIdx.x & 63;
    const int wave = threadIdx.x >> 6;
    const int m = lane & 15, quad = lane >> 4;
    const long pxA = (long)blockIdx.x * 128 + wave * 16 + m;
    const long pxB = pxA + 64;
    const int b = (int)(((long)blockIdx.x * 128) >> 16);
    const float* wa = watt + b * 128;
    const int sA = wave, sB = wave + 4;

    // residual x loads first (both groups): latency hides under t-load + pw2
    f32x4 xvA[4], xvB[4];
#pragma unroll
    for (int nt = 0; nt < 4; ++nt) {
        xvA[nt] = *(const f32x4*)(x + pxA * 64 + nt * 16 + quad * 4);
        xvB[nt] = *(const f32x4*)(x + pxB * 64 + nt * 16 + quad * 4);
    }

    const short* trA = t + pxA * 128;
    const short* trB = t + pxB * 128;
    f32x4 acc2A[4], acc2B[4];
#pragma unroll
    for (int nt = 0; nt < 4; ++nt) {
        acc2A[nt] = (f32x4){0.f,0.f,0.f,0.f};
        acc2B[nt] = (f32x4){0.f,0.f,0.f,0.f};
    }
#pragma unroll
    for (int kh = 0; kh < 4; ++kh) {
        uint4_t tA = *(const uint4_t*)(trA + kh * 32 + quad * 8);
        uint4_t tB = *(const uint4_t*)(trB + kh * 32 + quad * 8);
        f32x4 w0  = *(const f32x4*)(wa + kh * 32 + quad * 8);
        f32x4 w1v = *(const f32x4*)(wa + kh * 32 + quad * 8 + 4);
        h2 s01 = pkrtz(w0[0], w0[1]),  s23 = pkrtz(w0[2], w0[3]);
        h2 s45 = pkrtz(w1v[0], w1v[1]), s67 = pkrtz(w1v[2], w1v[3]);
        uint4_t oA, oB;
        oA[0] = h2u(u2h(tA[0]) * s01); oA[1] = h2u(u2h(tA[1]) * s23);
        oA[2] = h2u(u2h(tA[2]) * s45); oA[3] = h2u(u2h(tA[3]) * s67);
        oB[0] = h2u(u2h(tB[0]) * s01); oB[1] = h2u(u2h(tB[1]) * s23);
        oB[2] = h2u(u2h(tB[2]) * s45); oB[3] = h2u(u2h(tB[3]) * s67);
        f16x8 bfrA = __builtin_bit_cast(f16x8, oA);
        f16x8 bfrB = __builtin_bit_cast(f16x8, oB);
#pragma unroll
        for (int nt = 0; nt < 4; ++nt) {
            f16x8 aw = __builtin_bit_cast(f16x8,
                *(const uint4_t*)(w2t + (nt * 16 + m) * 128 + kh * 32 + quad * 8));
            acc2A[nt] = __builtin_amdgcn_mfma_f32_16x16x32_f16(aw, bfrA, acc2A[nt], 0, 0, 0);
            acc2B[nt] = __builtin_amdgcn_mfma_f32_16x16x32_f16(aw, bfrB, acc2B[nt], 0, 0, 0);
        }
    }
    float x1A[4][4], x1B[4][4];
#pragma unroll
    for (int nt = 0; nt < 4; ++nt) {
        int cob = nt * 16 + quad * 4;
        f32x4 bb = *(const f32x4*)(b2 + cob);
        f32x4 be = *(const f32x4*)(beta + cob);
#pragma unroll
        for (int r = 0; r < 4; ++r) {
            x1A[nt][r] = xvA[nt][r] + (acc2A[nt][r] + bb[r]) * be[r];
            x1B[nt][r] = xvB[nt][r] + (acc2B[nt][r] + bb[r]) * be[r];
        }
    }
    // LN2 for both groups
    float sa = 0.f, s2a = 0.f, sb = 0.f, s2b = 0.f;
#pragma unroll
    for (int nt = 0; nt < 4; ++nt)
#pragma unroll
        for (int r = 0; r < 4; ++r) {
            sa += x1A[nt][r]; s2a += x1A[nt][r] * x1A[nt][r];
            sb += x1B[nt][r]; s2b += x1B[nt][r] * x1B[nt][r];
        }
    sa  += __shfl_xor(sa, 16);  sa  += __shfl_xor(sa, 32);
    s2a += __shfl_xor(s2a, 16); s2a += __shfl_xor(s2a, 32);
    sb  += __shfl_xor(sb, 16);  sb  += __shfl_xor(sb, 32);
    s2b += __shfl_xor(s2b, 16); s2b += __shfl_xor(s2b, 32);
    float meanA = sa * 0.015625f;
    float varA  = s2a * 0.015625f - meanA * meanA;
    float rsA   = rsqrtf(varA + 1e-6f);
    float mrsA  = meanA * rsA;
    float meanB = sb * 0.015625f;
    float varB  = s2b * 0.015625f - meanB * meanB;
    float rsB   = rsqrtf(varB + 1e-6f);
    float mrsB  = meanB * rsB;
#pragma unroll
    for (int nt = 0; nt < 4; ++nt) {
        int cob = nt * 16 + quad * 4;
        f32x4 gg = *(const f32x4*)(ln2g + cob);
        f32x4 cc = *(const f32x4*)(ln2b + cob);
        uint2_t pkA, pkB;
        pkA[0] = h2u(pkrtz((x1A[nt][0] * rsA - mrsA) * gg[0] + cc[0],
                           (x1A[nt][1] * rsA - mrsA) * gg[1] + cc[1]));
        pkA[1] = h2u(pkrtz((x1A[nt][2] * rsA - mrsA) * gg[2] + cc[2],
                           (x1A[nt][3] * rsA - mrsA) * gg[3] + cc[3]));
        pkB[0] = h2u(pkrtz((x1B[nt][0] * rsB - mrsB) * gg[0] + cc[0],
                           (x1B[nt][1] * rsB - mrsB) * gg[1] + cc[1]));
        pkB[1] = h2u(pkrtz((x1B[nt][2] * rsB - mrsB) * gg[2] + cc[2],
                           (x1B[nt][3] * rsB - mrsB) * gg[3] + cc[3]));
        *(uint2_t*)&xz[sA][m * ZTST + cob] = pkA;
        *(uint2_t*)&xz[sB][m * ZTST + cob] = pkB;
    }
    // no barrier: slabs are wave-private; DS in-order per wave
    f16x8 xbA0 = __builtin_bit_cast(f16x8, *(const uint4_t*)&xz[sA][m * ZTST + quad * 8]);
    f16x8 xbA1 = __builtin_bit_cast(f16x8, *(const uint4_t*)&xz[sA][m * ZTST + 32 + quad * 8]);
    f16x8 xbB0 = __builtin_bit_cast(f16x8, *(const uint4_t*)&xz[sB][m * ZTST + quad * 8]);
    f16x8 xbB1 = __builtin_bit_cast(f16x8, *(const uint4_t*)&xz[sB][m * ZTST + 32 + quad * 8]);
    // from here xz rows are dead (consumed into registers) -> reuse for zt
#pragma unroll
    for (int pg = 0; pg < 8; ++pg) {
        f16x8 w3a0 = __builtin_bit_cast(f16x8, *(const uint4_t*)(w3t + (pg * 16 + m) * 64 + quad * 8));
        f16x8 w3a1 = __builtin_bit_cast(f16x8, *(const uint4_t*)(w3t + (pg * 16 + m) * 64 + 32 + quad * 8));
        f16x8 w3b0 = __builtin_bit_cast(f16x8, *(const uint4_t*)(w3t + (128 + pg * 16 + m) * 64 + quad * 8));
        f16x8 w3b1 = __builtin_bit_cast(f16x8, *(const uint4_t*)(w3t + (128 + pg * 16 + m) * 64 + 32 + quad * 8));
        f32x4 aAA = {0.f,0.f,0.f,0.f}, aBA = {0.f,0.f,0.f,0.f};
        f32x4 aAB = {0.f,0.f,0.f,0.f}, aBB = {0.f,0.f,0.f,0.f};
        aAA = __builtin_amdgcn_mfma_f32_16x16x32_f16(w3a0, xbA0, aAA, 0, 0, 0);
        aAA = __builtin_amdgcn_mfma_f32_16x16x32_f16(w3a1, xbA1, aAA, 0, 0, 0);
        aBA = __builtin_amdgcn_mfma_f32_16x16x32_f16(w3b0, xbA0, aBA, 0, 0, 0);
        aBA = __builtin_amdgcn_mfma_f32_16x16x32_f16(w3b1, xbA1, aBA, 0, 0, 0);
        aAB = __builtin_amdgcn_mfma_f32_16x16x32_f16(w3a0, xbB0, aAB, 0, 0, 0);
        aAB = __builtin_amdgcn_mfma_f32_16x16x32_f16(w3a1, xbB1, aAB, 0, 0, 0);
        aBB = __builtin_amdgcn_mfma_f32_16x16x32_f16(w3b0, xbB0, aBB, 0, 0, 0);
        aBB = __builtin_amdgcn_mfma_f32_16x16x32_f16(w3b1, xbB1, aBB, 0, 0, 0);
        int cb = pg * 16 + quad * 4;
        f32x4 bA_ = *(const f32x4*)(b3 + cb);
        f32x4 bB_ = *(const f32x4*)(b3 + 128 + cb);
        uint2_t pkA, pkB;
        pkA[0] = h2u(pkrtz((aAA[0] + bA_[0]) * (aBA[0] + bB_[0]),
                           (aAA[1] + bA_[1]) * (aBA[1] + bB_[1])));
        pkA[1] = h2u(pkrtz((aAA[2] + bA_[2]) * (aBA[2] + bB_[2]),
                           (aAA[3] + bA_[3]) * (aBA[3] + bB_[3])));
        pkB[0] = h2u(pkrtz((aAB[0] + bA_[0]) * (aBB[0] + bB_[0]),
                           (aAB[1] + bA_[1]) * (aBB[1] + bB_[1])));
        pkB[1] = h2u(pkrtz((aAB[2] + bA_[2]) * (aBB[2] + bB_[2]),
                           (aAB[3] + bA_[3]) * (aBB[3] + bB_[3])));
        *(uint2_t*)&xz[sA][m * ZTST + cb] = pkA;
        *(uint2_t*)&xz[sB][m * ZTST + cb] = pkB;
    }
    // no barrier: slabs are wave-private
    f32x4 acc4A[4], acc4B[4];
#pragma unroll
    for (int nt = 0; nt < 4; ++nt) {
        acc4A[nt] = (f32x4){0.f,0.f,0.f,0.f};
        acc4B[nt] = (f32x4){0.f,0.f,0.f,0.f};
    }
#pragma unroll
    for (int kh = 0; kh < 4; ++kh) {
        f16x8 zbA = __builtin_bit_cast(f16x8, *(const uint4_t*)&xz[sA][m * ZTST + kh * 32 + quad * 8]);
        f16x8 zbB = __builtin_bit_cast(f16x8, *(const uint4_t*)&xz[sB][m * ZTST + kh * 32 + quad * 8]);
#pragma unroll
        for (int nt = 0; nt < 4; ++nt) {
            f16x8 aw = __builtin_bit_cast(f16x8,
                *(const uint4_t*)(w4t + (nt * 16 + m) * 128 + kh * 32 + quad * 8));
            acc4A[nt] = __builtin_amdgcn_mfma_f32_16x16x32_f16(aw, zbA, acc4A[nt], 0, 0, 0);
            acc4B[nt] = __builtin_amdgcn_mfma_f32_16x16x32_f16(aw, zbB, acc4B[nt], 0, 0, 0);
        }
    }
#pragma unroll
    for (int nt = 0; nt < 4; ++nt) {
        int cob = nt * 16 + quad * 4;
        f32x4 bb = *(const f32x4*)(b4 + cob);
        f32x4 gm = *(const f32x4*)(gamma + cob);
        f32x4 oA, oB;
#pragma unroll
        for (int r = 0; r < 4; ++r) {
            oA[r] = x1A[nt][r] + (acc4A[nt][r] + bb[r]) * gm[r];
            oB[r] = x1B[nt][r] + (acc4B[nt][r] + bb[r]) * gm[r];
        }
        *(f32x4*)(out + pxA * 64 + cob) = oA;
        *(f32x4*)(out + pxB * 64 + cob) = oB;
    }
}

// ---------- launch ----------
extern "C" void kernel_launch(void* const* d_in, const int* in_sizes, int n_in,
                              void* d_out, int out_size, void* d_ws, size_t ws_size,
                              hipStream_t stream) {
    (void)in_sizes; (void)n_in; (void)out_size; (void)ws_size;
    const float* x    = (const float*)d_in[0];
    const float* ln1g = (const float*)d_in[1];
    const float* ln1b = (const float*)d_in[2];
    const float* pw1w = (const float*)d_in[3];
    const float* pw1b = (const float*)d_in[4];
    const float* dww  = (const float*)d_in[5];
    const float* dwb  = (const float*)d_in[6];
    const float* scaw = (const float*)d_in[7];
    const float* scab = (const float*)d_in[8];
    const float* pw2w = (const float*)d_in[9];
    const float* pw2b = (const float*)d_in[10];
    const float* beta = (const float*)d_in[11];
    const float* ln2g = (const float*)d_in[12];
    const float* ln2b = (const float*)d_in[13];
    const float* pw3w = (const float*)d_in[14];
    const float* pw3b = (const float*)d_in[15];
    const float* pw4w = (const float*)d_in[16];
    const float* pw4b = (const float*)d_in[17];
    const float* gamma= (const float*)d_in[18];

    char* ws = (char*)d_ws;
    short* w1t = (short*)(ws + OFF_W1T);
    short* w2t = (short*)(ws + OFF_W2T);
    short* w3t = (short*)(ws + OFF_W3T);
    short* w4t = (short*)(ws + OFF_W4T);
    short* dwh = (short*)(ws + OFF_DWH);
    short* dbh = (short*)(ws + OFF_DBH);
    float* watt = (float*)(ws + OFF_WATT);
    float* gpart = (float*)(ws + OFF_GPART);
    float* gpart2 = (float*)(ws + OFF_GPART2);
    short* t   = (short*)(ws + OFF_T);
    float* out = (float*)d_out;

    k_prep<<<64, 256, 0, stream>>>(pw1w, pw2w, pw3w, pw4w, dww, dwb,
                                   w1t, w2t, w3t, w4t, dwh, dbh);
    k_a<<<16384, 256, 0, stream>>>(x, ln1g, ln1b, w1t, pw1b, dwh, dbh, t, gpart);
    k_red2<<<64, 256, 0, stream>>>(gpart, gpart2);
    k_sca3<<<8, 256, 0, stream>>>(gpart2, scaw, scab, watt);
    k_b<<<4096, 256, 0, stream>>>(t, watt, w2t, pw2b, x, beta, ln2g, ln2b,
                                  w3t, pw3b, w4t, pw4b, gamma, out);
}